// Round 8
// baseline (1597.180 us; speedup 1.0000x reference)
//
#include <hip/hip_runtime.h>

#define NITER   5
#define B_G     16
#define NPG     3125
#define EPG     50000
#define NNODES  50000
#define NEDGES  800000
#define FD      32
#define HD      64

#define EDGE_TPG   391          // tiles of 128 edges per graph: ceil(50000/128)
#define EDGE_BLOCKS 1024        // 8 XCDs x 128; 64 blocks per graph

#define NODE_TPG   25           // tiles of 128 nodes per graph
#define NODE_BLOCKS (B_G * NODE_TPG)

typedef __attribute__((ext_vector_type(4))) float f32x4;
typedef __attribute__((ext_vector_type(8))) short bf16x8;
typedef __attribute__((ext_vector_type(4))) unsigned int u32x4;

union FragU { bf16x8 v; unsigned int u[4]; u32x4 q; };

// Truncation-based hi/lo split: hi = top16(f), lo = top16(f - hi).
__device__ __forceinline__ void fsplit2(float a, float b,
                                        unsigned int& hi, unsigned int& lo) {
    unsigned int ua = __float_as_uint(a), ub = __float_as_uint(b);
    float la = a - __uint_as_float(ua & 0xffff0000u);
    float lb = b - __uint_as_float(ub & 0xffff0000u);
    hi = __builtin_amdgcn_perm(ub, ua, 0x07060302u);
    lo = __builtin_amdgcn_perm(__float_as_uint(lb), __float_as_uint(la), 0x07060302u);
}
__device__ __forceinline__ unsigned int fpack_hl(float v) {
    unsigned int uv = __float_as_uint(v);
    float lv = v - __uint_as_float(uv & 0xffff0000u);
    return __builtin_amdgcn_perm(__float_as_uint(lv), uv, 0x07060302u);
}
__device__ __forceinline__ bf16x8 ldfrag(const unsigned int* p) {
    FragU t; t.q = *(const u32x4*)p; return t.v;
}
__device__ __forceinline__ f32x4 mfma16(bf16x8 a, bf16x8 b, f32x4 c) {
    return __builtin_amdgcn_mfma_f32_16x16x32_bf16(a, b, c, 0, 0, 0);
}

// ---------------- weight fragment pre-split (once per call) ----------------
// wsp dword layout: E1 (12 frag-pairs) @0, E2-PERMUTED (4) @6144,
//                   N1 (8) @8192, N2 (4) @12288.
__global__ __launch_bounds__(1024) void wsplit_kernel(
    const float* __restrict__ We1, const float* __restrict__ We2,
    const float* __restrict__ Wn1, const float* __restrict__ Wn2,
    unsigned int* __restrict__ wsp)
{
    for (int item = threadIdx.x; item < 1792; item += 1024) {
        int l = item & 63;
        int lm = l & 15, lg = l >> 4;
        if (item < 768) {                       // E1 (A-side W1^T frags)
            int f = item >> 6; int s = f >> 2, n = f & 3;
            unsigned int* dst = wsp + f * 512;
            int rowbase = s * 32 + lg * 8;
            int col = n * 16 + lm;
            #pragma unroll
            for (int p = 0; p < 4; ++p) {
                unsigned int hi, lo;
                fsplit2(We1[(rowbase + 2*p) * HD + col],
                        We1[(rowbase + 2*p + 1) * HD + col], hi, lo);
                dst[l*4 + p] = hi; dst[256 + l*4 + p] = lo;
            }
        } else if (item < 1024) {               // E2 permuted (A-side W2^T, custom k-order)
            int f = (item - 768) >> 6; int s2 = f >> 1, n2 = f & 1;
            unsigned int* dst = wsp + 6144 + f * 512;
            int col = n2 * 16 + lm;
            #pragma unroll
            for (int p = 0; p < 4; ++p) {
                int m  = 2 * s2 + (p >> 1);
                int j0 = m * 16 + lg * 4 + ((2*p) & 3);
                unsigned int hi, lo;
                fsplit2(We2[j0 * FD + col], We2[(j0 + 1) * FD + col], hi, lo);
                dst[l*4 + p] = hi; dst[256 + l*4 + p] = lo;
            }
        } else if (item < 1536) {               // N1 (old layout, node kernel)
            int f = (item - 1024) >> 6; int s = f >> 2, n = f & 3;
            unsigned int* dst = wsp + 8192 + f * 512;
            int rowbase = s * 32 + lg * 8;
            int col = n * 16 + lm;
            #pragma unroll
            for (int p = 0; p < 4; ++p) {
                unsigned int hi, lo;
                fsplit2(Wn1[(rowbase + 2*p) * HD + col],
                        Wn1[(rowbase + 2*p + 1) * HD + col], hi, lo);
                dst[l*4 + p] = hi; dst[256 + l*4 + p] = lo;
            }
        } else {                                // N2 (old layout, node kernel)
            int f = (item - 1536) >> 6; int s = f >> 1, n = f & 1;
            unsigned int* dst = wsp + 12288 + f * 512;
            int rowbase = s * 32 + lg * 8;
            int col = n * 16 + lm;
            #pragma unroll
            for (int p = 0; p < 4; ++p) {
                unsigned int hi, lo;
                fsplit2(Wn2[(rowbase + 2*p) * FD + col],
                        Wn2[(rowbase + 2*p + 1) * FD + col], hi, lo);
                dst[l*4 + p] = hi; dst[256 + l*4 + p] = lo;
            }
        }
    }
}

// ---------------- x pre-split (per iteration): [hi 16dw | lo 16dw] per node ----
__global__ __launch_bounds__(256) void xsplit_kernel(
    const float* __restrict__ xin, unsigned int* __restrict__ x_sp)
{
    int t = blockIdx.x * 256 + threadIdx.x;
    if (t >= NNODES * 4) return;
    int n = t >> 2, c = t & 3;
    long base = (long)n * 32 + c * 8;
    f32x4 a = *(const f32x4*)(xin + base);
    f32x4 b = *(const f32x4*)(xin + base + 4);
    unsigned int h[4], lo[4];
    fsplit2(a[0], a[1], h[0], lo[0]);
    fsplit2(a[2], a[3], h[1], lo[1]);
    fsplit2(b[0], b[1], h[2], lo[2]);
    fsplit2(b[2], b[3], h[3], lo[3]);
    *(u32x4*)(x_sp + (long)n * 32 + c * 4)      = (u32x4){h[0], h[1], h[2], h[3]};
    *(u32x4*)(x_sp + (long)n * 32 + 16 + c * 4) = (u32x4){lo[0], lo[1], lo[2], lo[3]};
}

// ---------------- CSR build (once per call) ----------------

__global__ __launch_bounds__(256) void count_kernel(const int* __restrict__ coli,
                                                    int* __restrict__ cnt)
{
    int e = blockIdx.x * 256 + threadIdx.x;
    if (e < NEDGES) atomicAdd(&cnt[coli[e]], 1);
}

__global__ __launch_bounds__(1024) void scan_blocks_kernel(const int* __restrict__ deg,
                                                           int* __restrict__ off,
                                                           int* __restrict__ bsum, int n)
{
    __shared__ int buf[1024];
    int tid = threadIdx.x;
    int idx = blockIdx.x * 1024 + tid;
    int v = (idx < n) ? deg[idx] : 0;
    buf[tid] = v;
    __syncthreads();
    for (int o = 1; o < 1024; o <<= 1) {
        int t = (tid >= o) ? buf[tid - o] : 0;
        __syncthreads();
        buf[tid] += t;
        __syncthreads();
    }
    if (idx < n) off[idx] = buf[tid] - v;
    if (tid == 1023) bsum[blockIdx.x] = buf[1023];
}

__global__ __launch_bounds__(64) void scan_carry_kernel(int* __restrict__ bsum,
                                                        int* __restrict__ off,
                                                        int nb, int n)
{
    if (threadIdx.x == 0) {
        int c = 0;
        for (int i = 0; i < nb; ++i) { int t = bsum[i]; bsum[i] = c; c += t; }
        off[n] = c;
    }
}

__global__ __launch_bounds__(1024) void scan_add_kernel(const int* __restrict__ bsum,
                                                        int* __restrict__ off, int n)
{
    int idx = blockIdx.x * 1024 + threadIdx.x;
    if (idx < n) off[idx] += bsum[blockIdx.x];
}

__global__ __launch_bounds__(256) void fill_kernel(const int* __restrict__ coli,
                                                   const int* __restrict__ off,
                                                   int* __restrict__ cursor,
                                                   int* __restrict__ csr)
{
    int e = blockIdx.x * 256 + threadIdx.x;
    if (e < NEDGES) {
        int c = coli[e];
        int pos = atomicAdd(&cursor[c], 1);
        csr[off[c] + pos] = e;
    }
}

// ---------------- per-iteration kernels ----------------

__global__ __launch_bounds__(1024) void prep_kernel(
    const float* __restrict__ y,
    const float* __restrict__ We1, const float* __restrict__ be1,
    const float* __restrict__ Wn1, const float* __restrict__ bn1,
    float* __restrict__ cu_e, float* __restrict__ cu_n,
    float* __restrict__ xagg, float* __restrict__ eagg)
{
    int tid = threadIdx.x;
    if (tid < B_G * FD) xagg[tid] = 0.0f;
    else                eagg[tid - B_G * FD] = 0.0f;

    int g = tid >> 6;
    int j = tid & 63;
    float ae = be1[j];
    float an = bn1[j];
    for (int k = 0; k < FD; ++k) {
        float yv = y[g * FD + k];
        ae = fmaf(yv, We1[(96 + k) * HD + j], ae);
        an = fmaf(yv, Wn1[(64 + k) * HD + j], an);
    }
    cu_e[g * HD + j] = ae;
    cu_n[g * HD + j] = an;
}

// ---- MFMA edge kernel v4: serial-t halves (VGPR<=128, 4 waves/SIMD),
//      transpose-free layer-2, weights in LDS, nontemporal ea. ----
__global__ __launch_bounds__(256, 4) void edge_mfma_kernel(
    const unsigned int* __restrict__ x_sp,   // [node][hi16|lo16] dwords
    const float* __restrict__ ea_in,
    const int* __restrict__ rowi,
    const int* __restrict__ coli,
    const unsigned int* __restrict__ wsp,    // E1 @0, E2p @6144
    const float* __restrict__ be2,
    const float* __restrict__ cu_e,
    float* __restrict__ ea_out,
    float* __restrict__ eagg)
{
    __shared__ __align__(16) unsigned int wlds[8192];   // 32 KB: E1 + E2p
    {
        const u32x4* src = (const u32x4*)wsp;
        u32x4* dst = (u32x4*)wlds;
        #pragma unroll
        for (int i = 0; i < 8; ++i)
            dst[threadIdx.x + i * 256] = src[threadIdx.x + i * 256];
    }
    __syncthreads();

    const int tid = threadIdx.x;
    const int wid = tid >> 6;
    const int l   = tid & 63;
    const int lm  = l & 15;
    const int lg  = l >> 4;

    const int b   = blockIdx.x;
    const int xcd = b & 7;
    const int i   = b >> 3;
    const int g   = 2 * xcd + (i >> 6);
    const int j0  = i & 63;
    const long gbase = (long)g * EPG;
    const long gend  = gbase + EPG;

    f32x4 bias1[4];
    #pragma unroll
    for (int m = 0; m < 4; ++m)
        bias1[m] = *(const f32x4*)(cu_e + g * HD + m * 16 + lg * 4);
    f32x4 bias2[2];
    #pragma unroll
    for (int n2 = 0; n2 < 2; ++n2)
        bias2[n2] = *(const f32x4*)(be2 + n2 * 16 + lg * 4);

    f32x4 eacc0 = {0,0,0,0}, eacc1 = {0,0,0,0};

    // one 16-edge half-tile: all static indexing, minimal live state
    auto do_half = [&](long e0, int toff,
                       u32x4 h0, u32x4 l0, u32x4 h1, u32x4 l1,
                       f32x4 v0, f32x4 v1) {
        f32x4 acc1[4];
        #pragma unroll
        for (int m = 0; m < 4; ++m) acc1[m] = bias1[m];

        // layer 1, x-src segment (s=0)
        #pragma unroll
        for (int m = 0; m < 4; ++m) {
            bf16x8 wh = ldfrag(wlds + m * 512 + l * 4);
            bf16x8 wl = ldfrag(wlds + m * 512 + 256 + l * 4);
            FragU bh, bl; bh.q = h0; bl.q = l0;
            acc1[m] = mfma16(wh, bh.v, acc1[m]);
            acc1[m] = mfma16(wl, bh.v, acc1[m]);
            acc1[m] = mfma16(wh, bl.v, acc1[m]);
        }
        // layer 1, x-dst segment (s=1)
        #pragma unroll
        for (int m = 0; m < 4; ++m) {
            bf16x8 wh = ldfrag(wlds + (4 + m) * 512 + l * 4);
            bf16x8 wl = ldfrag(wlds + (4 + m) * 512 + 256 + l * 4);
            FragU bh, bl; bh.q = h1; bl.q = l1;
            acc1[m] = mfma16(wh, bh.v, acc1[m]);
            acc1[m] = mfma16(wl, bh.v, acc1[m]);
            acc1[m] = mfma16(wh, bl.v, acc1[m]);
        }
        // layer 1, ea segment (s=2)
        FragU beh, bel;
        fsplit2(v0[0], v0[1], beh.u[0], bel.u[0]);
        fsplit2(v0[2], v0[3], beh.u[1], bel.u[1]);
        fsplit2(v1[0], v1[1], beh.u[2], bel.u[2]);
        fsplit2(v1[2], v1[3], beh.u[3], bel.u[3]);
        #pragma unroll
        for (int m = 0; m < 4; ++m) {
            bf16x8 wh = ldfrag(wlds + (8 + m) * 512 + l * 4);
            bf16x8 wl = ldfrag(wlds + (8 + m) * 512 + 256 + l * 4);
            acc1[m] = mfma16(wh, beh.v, acc1[m]);
            acc1[m] = mfma16(wl, beh.v, acc1[m]);
            acc1[m] = mfma16(wh, bel.v, acc1[m]);
        }

        // B2 frags: relu + split, lane-local (k-order matches permuted W2)
        FragU b2h[2], b2l[2];
        #pragma unroll
        for (int s2 = 0; s2 < 2; ++s2)
            #pragma unroll
            for (int p = 0; p < 4; ++p) {
                int m = 2 * s2 + (p >> 1);
                int r = (2 * p) & 3;
                float a = fmaxf(acc1[m][r], 0.0f);
                float c = fmaxf(acc1[m][r + 1], 0.0f);
                fsplit2(a, c, b2h[s2].u[p], b2l[s2].u[p]);
            }

        // layer 2
        f32x4 acc2[2];
        acc2[0] = bias2[0]; acc2[1] = bias2[1];
        #pragma unroll
        for (int s2 = 0; s2 < 2; ++s2)
            #pragma unroll
            for (int n2 = 0; n2 < 2; ++n2) {
                bf16x8 wh = ldfrag(wlds + 6144 + (s2 * 2 + n2) * 512 + l * 4);
                bf16x8 wl = ldfrag(wlds + 6144 + (s2 * 2 + n2) * 512 + 256 + l * 4);
                acc2[n2] = mfma16(wh, b2h[s2].v, acc2[n2]);
                acc2[n2] = mfma16(wl, b2h[s2].v, acc2[n2]);
                acc2[n2] = mfma16(wh, b2l[s2].v, acc2[n2]);
            }

        // store (nontemporal; lane owns edge lm of this half) + eagg accumulate
        int local = toff + lm;
        if (local < (int)(gend - e0)) {
            float* po = ea_out + (e0 + local) * FD + lg * 4;
            __builtin_nontemporal_store(acc2[0], (f32x4*)po);
            __builtin_nontemporal_store(acc2[1], (f32x4*)(po + 16));
            eacc0 += acc2[0];
            eacc1 += acc2[1];
        }
    };

    int nrr[2], ncc[2];
    #pragma unroll
    for (int t = 0; t < 2; ++t) {
        long e = gbase + (long)j0 * 128 + wid * 32 + t * 16 + lm;
        if (e >= gend) e = gend - 1;
        nrr[t] = rowi[e]; ncc[t] = coli[e];
    }

    for (int lt = j0; lt < EDGE_TPG; lt += 64) {
        int rr0 = nrr[0], rr1 = nrr[1], cc0 = ncc[0], cc1 = ncc[1];
        int nlt = lt + 64;
        if (nlt < EDGE_TPG) {
            #pragma unroll
            for (int t = 0; t < 2; ++t) {
                long e = gbase + (long)nlt * 128 + wid * 32 + t * 16 + lm;
                if (e >= gend) e = gend - 1;
                nrr[t] = rowi[e]; ncc[t] = coli[e];
            }
        }
        const long e0 = gbase + (long)lt * 128 + wid * 32;

        // issue ALL gathers for both halves up front
        const unsigned int* pr0 = x_sp + (long)rr0 * 32;
        const unsigned int* pc0 = x_sp + (long)cc0 * 32;
        const unsigned int* pr1 = x_sp + (long)rr1 * 32;
        const unsigned int* pc1 = x_sp + (long)cc1 * 32;
        u32x4 h00 = *(const u32x4*)(pr0 + lg * 4);
        u32x4 l00 = *(const u32x4*)(pr0 + 16 + lg * 4);
        u32x4 h01 = *(const u32x4*)(pc0 + lg * 4);
        u32x4 l01 = *(const u32x4*)(pc0 + 16 + lg * 4);
        u32x4 h10 = *(const u32x4*)(pr1 + lg * 4);
        u32x4 l10 = *(const u32x4*)(pr1 + 16 + lg * 4);
        u32x4 h11 = *(const u32x4*)(pc1 + lg * 4);
        u32x4 l11 = *(const u32x4*)(pc1 + 16 + lg * 4);

        long ee0 = e0 + lm;       if (ee0 >= gend) ee0 = gend - 1;
        long ee1 = e0 + 16 + lm;  if (ee1 >= gend) ee1 = gend - 1;
        const float* pe0 = ea_in + ee0 * FD + lg * 8;
        const float* pe1 = ea_in + ee1 * FD + lg * 8;
        f32x4 v00 = __builtin_nontemporal_load((const f32x4*)pe0);
        f32x4 v01 = __builtin_nontemporal_load((const f32x4*)(pe0 + 4));
        f32x4 v10 = __builtin_nontemporal_load((const f32x4*)pe1);
        f32x4 v11 = __builtin_nontemporal_load((const f32x4*)(pe1 + 4));

        do_half(e0, 0,  h00, l00, h01, l01, v00, v01);
        do_half(e0, 16, h10, l10, h11, l11, v10, v11);
    }

    // eagg: reduce across the 16 lm lanes, one atomic batch per wave
    #pragma unroll
    for (int r = 0; r < 4; ++r) {
        float v0 = eacc0[r], v1 = eacc1[r];
        v0 += __shfl_xor(v0, 1, 64); v1 += __shfl_xor(v1, 1, 64);
        v0 += __shfl_xor(v0, 2, 64); v1 += __shfl_xor(v1, 2, 64);
        v0 += __shfl_xor(v0, 4, 64); v1 += __shfl_xor(v1, 4, 64);
        v0 += __shfl_xor(v0, 8, 64); v1 += __shfl_xor(v1, 8, 64);
        if (lm == 0) {
            atomicAdd(&eagg[g * FD + lg * 4 + r], v0);
            atomicAdd(&eagg[g * FD + 16 + lg * 4 + r], v1);
        }
    }
}

// ---- aggregation: wave per node; 8 rows x 8 feat-quads; nontemporal gather ----
__global__ __launch_bounds__(256) void agg_kernel(
    const float* __restrict__ ea,
    const int* __restrict__ off,
    const int* __restrict__ csr,
    float* __restrict__ e_mean)
{
    int wid = threadIdx.x >> 6;
    int l   = threadIdx.x & 63;
    int rq  = l >> 3;
    int q   = l & 7;
    int n = blockIdx.x * 4 + wid;
    int s0 = off[n], s1 = off[n + 1];
    int deg = s1 - s0;

    f32x4 acc = {0.0f, 0.0f, 0.0f, 0.0f};
    if (deg > 0) {
        int cl = (l < deg) ? l : 0;
        int cidx = csr[s0 + cl];
        #pragma unroll
        for (int r = 0; r < 8; ++r) {
            int src = r * 8 + rq;
            int eid = __shfl(cidx, src, 64);
            if (src < deg) {
                f32x4 v = __builtin_nontemporal_load(
                    (const f32x4*)(ea + (long)eid * FD + q * 4));
                acc += v;
            }
        }
        if (deg > 64) {
            for (int i = s0 + 64; i < s1; i += 8) {
                int ii = i + rq;
                if (ii < s1) {
                    int eid = csr[ii];
                    acc += __builtin_nontemporal_load(
                        (const f32x4*)(ea + (long)eid * FD + q * 4));
                }
            }
        }
    }
    #pragma unroll
    for (int m = 8; m < 64; m <<= 1) {
        acc[0] += __shfl_xor(acc[0], m, 64);
        acc[1] += __shfl_xor(acc[1], m, 64);
        acc[2] += __shfl_xor(acc[2], m, 64);
        acc[3] += __shfl_xor(acc[3], m, 64);
    }
    float inv = 1.0f / (float)(deg > 1 ? deg : 1);
    if (l < 8) {
        f32x4 o = {acc[0] * inv, acc[1] * inv, acc[2] * inv, acc[3] * inv};
        *(f32x4*)(e_mean + (long)n * FD + q * 4) = o;
    }
}

// ---- MFMA node kernel (old structure, unchanged) ----
__global__ __launch_bounds__(256) void node_mfma_kernel(
    const float* __restrict__ x_in,
    const float* __restrict__ e_mean,
    const unsigned int* __restrict__ wsp,  // N1 @0 (rel), N2 @4096 (rel)
    const float* __restrict__ bn2,
    const float* __restrict__ cu_n,
    float* __restrict__ x_out,
    float* __restrict__ xagg)
{
    __shared__ unsigned int h_lds[4][32][68];

    const int tid = threadIdx.x;
    const int wid = tid >> 6;
    const int l   = tid & 63;
    const int lm  = l & 15;
    const int lg  = l >> 4;
    const int koff = lg * 8;

    bf16x8 w1h[2][4], w1l[2][4];
    #pragma unroll
    for (int s = 0; s < 2; ++s)
        #pragma unroll
        for (int n = 0; n < 4; ++n) {
            const unsigned int* p = wsp + (s * 4 + n) * 512 + l * 4;
            w1h[s][n] = ldfrag(p);
            w1l[s][n] = ldfrag(p + 256);
        }
    bf16x8 w2h[2][2], w2l[2][2];
    #pragma unroll
    for (int s = 0; s < 2; ++s)
        #pragma unroll
        for (int n = 0; n < 2; ++n) {
            const unsigned int* p = wsp + 4096 + (s * 2 + n) * 512 + l * 4;
            w2h[s][n] = ldfrag(p);
            w2l[s][n] = ldfrag(p + 256);
        }
    float bias2[2];
    bias2[0] = bn2[lm];
    bias2[1] = bn2[16 + lm];

    const int g  = blockIdx.x / NODE_TPG;
    const int lt = blockIdx.x - g * NODE_TPG;
    const int nb = lt * 128 + wid * 32;

    f32x4 va[2][2][2];
    #pragma unroll
    for (int t = 0; t < 2; ++t) {
        int rl = nb + t * 16 + lm;
        if (rl > NPG - 1) rl = NPG - 1;
        long node = (long)g * NPG + rl;
        const float* p0 = x_in   + node * FD + koff;
        const float* p1 = e_mean + node * FD + koff;
        va[t][0][0] = *(const f32x4*)p0; va[t][0][1] = *(const f32x4*)(p0 + 4);
        va[t][1][0] = *(const f32x4*)p1; va[t][1][1] = *(const f32x4*)(p1 + 4);
    }

    f32x4 acc1[2][4];
    #pragma unroll
    for (int n = 0; n < 4; ++n) {
        float b = cu_n[g * HD + n * 16 + lm];
        #pragma unroll
        for (int t = 0; t < 2; ++t) acc1[t][n] = (f32x4){b, b, b, b};
    }

    #pragma unroll
    for (int t = 0; t < 2; ++t) {
        #pragma unroll
        for (int s = 0; s < 2; ++s) {
            FragU ah, al;
            #pragma unroll
            for (int q = 0; q < 2; ++q)
                #pragma unroll
                for (int p = 0; p < 2; ++p)
                    fsplit2(va[t][s][q][2 * p], va[t][s][q][2 * p + 1],
                            ah.u[q * 2 + p], al.u[q * 2 + p]);
            #pragma unroll
            for (int n = 0; n < 4; ++n) {
                acc1[t][n] = mfma16(ah.v, w1h[s][n], acc1[t][n]);
                acc1[t][n] = mfma16(ah.v, w1l[s][n], acc1[t][n]);
                acc1[t][n] = mfma16(al.v, w1h[s][n], acc1[t][n]);
            }
        }
    }

    #pragma unroll
    for (int t = 0; t < 2; ++t)
        #pragma unroll
        for (int n = 0; n < 4; ++n)
            #pragma unroll
            for (int r = 0; r < 4; ++r)
                h_lds[wid][t * 16 + lg * 4 + r][n * 16 + lm] =
                    fpack_hl(fmaxf(acc1[t][n][r], 0.0f));
    asm volatile("s_waitcnt lgkmcnt(0)" ::: "memory");
    __builtin_amdgcn_sched_barrier(0);

    f32x4 acc2[2][2];
    #pragma unroll
    for (int n = 0; n < 2; ++n) {
        #pragma unroll
        for (int t = 0; t < 2; ++t) acc2[t][n] = (f32x4){bias2[n], bias2[n], bias2[n], bias2[n]};
    }
    #pragma unroll
    for (int t = 0; t < 2; ++t) {
        #pragma unroll
        for (int s = 0; s < 2; ++s) {
            const unsigned int* hp = &h_lds[wid][t * 16 + lm][s * 32 + koff];
            unsigned int u0 = hp[0], u1 = hp[1], u2 = hp[2], u3 = hp[3];
            unsigned int u4 = hp[4], u5 = hp[5], u6 = hp[6], u7 = hp[7];
            FragU ah, al;
            ah.u[0] = __builtin_amdgcn_perm(u1, u0, 0x05040100u);
            ah.u[1] = __builtin_amdgcn_perm(u3, u2, 0x05040100u);
            ah.u[2] = __builtin_amdgcn_perm(u5, u4, 0x05040100u);
            ah.u[3] = __builtin_amdgcn_perm(u7, u6, 0x05040100u);
            al.u[0] = __builtin_amdgcn_perm(u1, u0, 0x07060302u);
            al.u[1] = __builtin_amdgcn_perm(u3, u2, 0x07060302u);
            al.u[2] = __builtin_amdgcn_perm(u5, u4, 0x07060302u);
            al.u[3] = __builtin_amdgcn_perm(u7, u6, 0x07060302u);
            #pragma unroll
            for (int n = 0; n < 2; ++n) {
                acc2[t][n] = mfma16(ah.v, w2h[s][n], acc2[t][n]);
                acc2[t][n] = mfma16(ah.v, w2l[s][n], acc2[t][n]);
                acc2[t][n] = mfma16(al.v, w2h[s][n], acc2[t][n]);
            }
        }
    }

    #pragma unroll
    for (int t = 0; t < 2; ++t)
        #pragma unroll
        for (int r = 0; r < 4; ++r) {
            int rl = nb + t * 16 + lg * 4 + r;
            if (rl < NPG) {
                long node = (long)g * NPG + rl;
                x_out[node * FD + lm]      = acc2[t][0][r];
                x_out[node * FD + 16 + lm] = acc2[t][1][r];
            }
        }

    #pragma unroll
    for (int n = 0; n < 2; ++n) {
        float s = 0.0f;
        #pragma unroll
        for (int t = 0; t < 2; ++t)
            #pragma unroll
            for (int r = 0; r < 4; ++r) {
                int rl = nb + t * 16 + lg * 4 + r;
                s += (rl < NPG) ? acc2[t][n][r] : 0.0f;
            }
        s += __shfl_xor(s, 16, 64);
        s += __shfl_xor(s, 32, 64);
        if (lg == 0) atomicAdd(&xagg[g * FD + n * 16 + lm], s);
    }
}

// ---- global MLP + fused prep + agg zeroing ----
__global__ __launch_bounds__(1024) void global_kernel(
    const float* __restrict__ y_in,
    float* __restrict__ xagg, float* __restrict__ eagg,
    const float* __restrict__ Wg1, const float* __restrict__ bg1,
    const float* __restrict__ Wg2, const float* __restrict__ bg2,
    const float* __restrict__ We1, const float* __restrict__ be1,
    const float* __restrict__ Wn1, const float* __restrict__ bn1,
    float* __restrict__ y_out,
    float* __restrict__ cu_e, float* __restrict__ cu_n)
{
    __shared__ float in_lds[B_G][100];
    __shared__ float h_lds2[B_G][HD + 1];
    __shared__ float y_lds[B_G][FD];
    int tid = threadIdx.x;
    for (int idx = tid; idx < B_G * 96; idx += 1024) {
        int g2 = idx / 96, k = idx % 96;
        float v;
        if (k < 32)      v = xagg[g2 * 32 + k] * (1.0f / NPG);
        else if (k < 64) v = eagg[g2 * 32 + (k - 32)] * (1.0f / EPG);
        else             v = y_in[g2 * 32 + (k - 64)];
        in_lds[g2][k] = v;
    }
    __syncthreads();
    int g = tid >> 6, j = tid & 63;
    float h = bg1[j];
    for (int k = 0; k < 96; ++k)
        h = fmaf(in_lds[g][k], Wg1[k * HD + j], h);
    h_lds2[g][j] = fmaxf(h, 0.0f);
    __syncthreads();
    if (j < FD) {
        float o = bg2[j];
        for (int k = 0; k < HD; ++k)
            o = fmaf(h_lds2[g][k], Wg2[k * FD + j], o);
        y_out[g * FD + j] = o;
        y_lds[g][j] = o;
    }
    __syncthreads();
    float ae = be1[j];
    float an = bn1[j];
    for (int k = 0; k < FD; ++k) {
        float yv = y_lds[g][k];
        ae = fmaf(yv, We1[(96 + k) * HD + j], ae);
        an = fmaf(yv, Wn1[(64 + k) * HD + j], an);
    }
    cu_e[g * HD + j] = ae;
    cu_n[g * HD + j] = an;
    if (tid < B_G * FD)            xagg[tid] = 0.0f;
    else if (tid < 2 * B_G * FD)   eagg[tid - B_G * FD] = 0.0f;
}

// ---------------- launch ----------------

extern "C" void kernel_launch(void* const* d_in, const int* in_sizes, int n_in,
                              void* d_out, int out_size, void* d_ws, size_t ws_size,
                              hipStream_t stream)
{
    const float* x0  = (const float*)d_in[0];
    const float* ea0 = (const float*)d_in[1];
    const float* y0  = (const float*)d_in[2];
    const float* We1 = (const float*)d_in[3];
    const float* be1 = (const float*)d_in[4];
    const float* We2 = (const float*)d_in[5];
    const float* be2 = (const float*)d_in[6];
    const float* Wn1 = (const float*)d_in[7];
    const float* bn1 = (const float*)d_in[8];
    const float* Wn2 = (const float*)d_in[9];
    const float* bn2 = (const float*)d_in[10];
    const float* Wg1 = (const float*)d_in[11];
    const float* bg1 = (const float*)d_in[12];
    const float* Wg2 = (const float*)d_in[13];
    const float* bg2 = (const float*)d_in[14];
    const int*   ei  = (const int*)d_in[15];
    const int* rowi = ei;
    const int* coli = ei + NEDGES;

    float* out_x  = (float*)d_out;
    float* out_ea = out_x + (size_t)NNODES * FD;
    float* out_y  = out_ea + (size_t)NEDGES * FD;

    char* ws = (char*)d_ws;
    int*   off    = (int*)(ws + 0);            // 50001 ints
    int*   cursor = (int*)(ws + 200192);       // 50000 ints
    int*   csr    = (int*)(ws + 400384);       // 800000 ints
    float* xagg   = (float*)(ws + 3600384);    // 16*32
    float* eagg   = xagg + B_G * FD;           // 16*32
    float* cu_e   = (float*)(ws + 3604480);    // 16*64
    float* cu_n   = cu_e + B_G * HD;           // 16*64
    float* e_mean = (float*)(ws + 3612672);    // 6.4 MB
    unsigned int* wsp = (unsigned int*)(ws + 10012672); // 57344 B
    int*   bsum   = (int*)(ws + 10070016);     // 256 B
    unsigned int* x_sp = (unsigned int*)(ws + 10070272); // 6.4 MB

    wsplit_kernel<<<1, 1024, 0, stream>>>(We1, We2, Wn1, Wn2, wsp);
    hipMemsetAsync(cursor, 0, NNODES * sizeof(int), stream);
    count_kernel<<<(NEDGES + 255) / 256, 256, 0, stream>>>(coli, cursor);
    scan_blocks_kernel<<<49, 1024, 0, stream>>>(cursor, off, bsum, NNODES);
    scan_carry_kernel<<<1, 64, 0, stream>>>(bsum, off, 49, NNODES);
    scan_add_kernel<<<49, 1024, 0, stream>>>(bsum, off, NNODES);
    hipMemsetAsync(cursor, 0, NNODES * sizeof(int), stream);
    fill_kernel<<<(NEDGES + 255) / 256, 256, 0, stream>>>(coli, off, cursor, csr);

    prep_kernel<<<1, 1024, 0, stream>>>(y0, We1, be1, Wn1, bn1,
                                        cu_e, cu_n, xagg, eagg);

    for (int it = 0; it < NITER; ++it) {
        const float* xc  = (it == 0) ? x0  : out_x;
        const float* eac = (it == 0) ? ea0 : out_ea;
        const float* yc  = (it == 0) ? y0  : out_y;

        xsplit_kernel<<<(NNODES * 4 + 255) / 256, 256, 0, stream>>>(xc, x_sp);
        edge_mfma_kernel<<<EDGE_BLOCKS, 256, 0, stream>>>(x_sp, eac, rowi, coli,
                                                          wsp, be2, cu_e,
                                                          out_ea, eagg);
        agg_kernel<<<NNODES / 4, 256, 0, stream>>>(out_ea, off, csr, e_mean);
        node_mfma_kernel<<<NODE_BLOCKS, 256, 0, stream>>>(xc, e_mean,
                                                          wsp + 8192, bn2, cu_n,
                                                          out_x, xagg);
        global_kernel<<<1, 1024, 0, stream>>>(yc, xagg, eagg,
                                              Wg1, bg1, Wg2, bg2,
                                              We1, be1, Wn1, bn1,
                                              out_y, cu_e, cu_n);
    }
}

// Round 9
// 750.279 us; speedup vs baseline: 2.1288x; 2.1288x over previous
//
#include <hip/hip_runtime.h>

#define NITER   5
#define B_G     16
#define NPG     3125
#define EPG     50000
#define NNODES  50000
#define NEDGES  800000
#define FD      32
#define HD      64

#define EDGE_TPG   391          // tiles of 128 edges per graph: ceil(50000/128)
#define EDGE_BLOCKS 1024        // 8 XCDs x 128; 64 blocks per graph

#define NODE_TPG   25           // tiles of 128 nodes per graph
#define NODE_BLOCKS (B_G * NODE_TPG)

typedef __attribute__((ext_vector_type(4))) float f32x4;
typedef __attribute__((ext_vector_type(8))) short bf16x8;
typedef __attribute__((ext_vector_type(4))) unsigned int u32x4;

union FragU { bf16x8 v; unsigned int u[4]; u32x4 q; };

// Truncation-based hi/lo split: hi = top16(f), lo = top16(f - hi).
__device__ __forceinline__ void fsplit2(float a, float b,
                                        unsigned int& hi, unsigned int& lo) {
    unsigned int ua = __float_as_uint(a), ub = __float_as_uint(b);
    float la = a - __uint_as_float(ua & 0xffff0000u);
    float lb = b - __uint_as_float(ub & 0xffff0000u);
    hi = __builtin_amdgcn_perm(ub, ua, 0x07060302u);
    lo = __builtin_amdgcn_perm(__float_as_uint(lb), __float_as_uint(la), 0x07060302u);
}
__device__ __forceinline__ unsigned int fpack_hl(float v) {
    unsigned int uv = __float_as_uint(v);
    float lv = v - __uint_as_float(uv & 0xffff0000u);
    return __builtin_amdgcn_perm(__float_as_uint(lv), uv, 0x07060302u);
}
__device__ __forceinline__ bf16x8 ldfrag(const unsigned int* p) {
    FragU t; t.q = *(const u32x4*)p; return t.v;
}
__device__ __forceinline__ f32x4 mfma16(bf16x8 a, bf16x8 b, f32x4 c) {
    return __builtin_amdgcn_mfma_f32_16x16x32_bf16(a, b, c, 0, 0, 0);
}

// ---------------- weight fragment pre-split (once per call) ----------------
// wsp dword layout: E1 (12 frag-pairs) @0, E2-PERMUTED (4) @6144,
//                   N1 (8) @8192, N2 (4) @12288.
__global__ __launch_bounds__(1024) void wsplit_kernel(
    const float* __restrict__ We1, const float* __restrict__ We2,
    const float* __restrict__ Wn1, const float* __restrict__ Wn2,
    unsigned int* __restrict__ wsp)
{
    for (int item = threadIdx.x; item < 1792; item += 1024) {
        int l = item & 63;
        int lm = l & 15, lg = l >> 4;
        if (item < 768) {                       // E1 (A-side W1^T frags)
            int f = item >> 6; int s = f >> 2, n = f & 3;
            unsigned int* dst = wsp + f * 512;
            int rowbase = s * 32 + lg * 8;
            int col = n * 16 + lm;
            #pragma unroll
            for (int p = 0; p < 4; ++p) {
                unsigned int hi, lo;
                fsplit2(We1[(rowbase + 2*p) * HD + col],
                        We1[(rowbase + 2*p + 1) * HD + col], hi, lo);
                dst[l*4 + p] = hi; dst[256 + l*4 + p] = lo;
            }
        } else if (item < 1024) {               // E2 permuted (A-side W2^T, custom k-order)
            int f = (item - 768) >> 6; int s2 = f >> 1, n2 = f & 1;
            unsigned int* dst = wsp + 6144 + f * 512;
            int col = n2 * 16 + lm;
            #pragma unroll
            for (int p = 0; p < 4; ++p) {
                int m  = 2 * s2 + (p >> 1);
                int j0 = m * 16 + lg * 4 + ((2*p) & 3);
                unsigned int hi, lo;
                fsplit2(We2[j0 * FD + col], We2[(j0 + 1) * FD + col], hi, lo);
                dst[l*4 + p] = hi; dst[256 + l*4 + p] = lo;
            }
        } else if (item < 1536) {               // N1 (old layout, node kernel)
            int f = (item - 1024) >> 6; int s = f >> 2, n = f & 3;
            unsigned int* dst = wsp + 8192 + f * 512;
            int rowbase = s * 32 + lg * 8;
            int col = n * 16 + lm;
            #pragma unroll
            for (int p = 0; p < 4; ++p) {
                unsigned int hi, lo;
                fsplit2(Wn1[(rowbase + 2*p) * HD + col],
                        Wn1[(rowbase + 2*p + 1) * HD + col], hi, lo);
                dst[l*4 + p] = hi; dst[256 + l*4 + p] = lo;
            }
        } else {                                // N2 (old layout, node kernel)
            int f = (item - 1536) >> 6; int s = f >> 1, n = f & 1;
            unsigned int* dst = wsp + 12288 + f * 512;
            int rowbase = s * 32 + lg * 8;
            int col = n * 16 + lm;
            #pragma unroll
            for (int p = 0; p < 4; ++p) {
                unsigned int hi, lo;
                fsplit2(Wn2[(rowbase + 2*p) * FD + col],
                        Wn2[(rowbase + 2*p + 1) * FD + col], hi, lo);
                dst[l*4 + p] = hi; dst[256 + l*4 + p] = lo;
            }
        }
    }
}

// ---------------- x pre-split (per iteration): [hi 16dw | lo 16dw] per node ----
__global__ __launch_bounds__(256) void xsplit_kernel(
    const float* __restrict__ xin, unsigned int* __restrict__ x_sp)
{
    int t = blockIdx.x * 256 + threadIdx.x;
    if (t >= NNODES * 4) return;
    int n = t >> 2, c = t & 3;
    long base = (long)n * 32 + c * 8;
    f32x4 a = *(const f32x4*)(xin + base);
    f32x4 b = *(const f32x4*)(xin + base + 4);
    unsigned int h[4], lo[4];
    fsplit2(a[0], a[1], h[0], lo[0]);
    fsplit2(a[2], a[3], h[1], lo[1]);
    fsplit2(b[0], b[1], h[2], lo[2]);
    fsplit2(b[2], b[3], h[3], lo[3]);
    *(u32x4*)(x_sp + (long)n * 32 + c * 4)      = (u32x4){h[0], h[1], h[2], h[3]};
    *(u32x4*)(x_sp + (long)n * 32 + 16 + c * 4) = (u32x4){lo[0], lo[1], lo[2], lo[3]};
}

// ---------------- CSR build (once per call) ----------------

__global__ __launch_bounds__(256) void count_kernel(const int* __restrict__ coli,
                                                    int* __restrict__ cnt)
{
    int e = blockIdx.x * 256 + threadIdx.x;
    if (e < NEDGES) atomicAdd(&cnt[coli[e]], 1);
}

__global__ __launch_bounds__(1024) void scan_blocks_kernel(const int* __restrict__ deg,
                                                           int* __restrict__ off,
                                                           int* __restrict__ bsum, int n)
{
    __shared__ int buf[1024];
    int tid = threadIdx.x;
    int idx = blockIdx.x * 1024 + tid;
    int v = (idx < n) ? deg[idx] : 0;
    buf[tid] = v;
    __syncthreads();
    for (int o = 1; o < 1024; o <<= 1) {
        int t = (tid >= o) ? buf[tid - o] : 0;
        __syncthreads();
        buf[tid] += t;
        __syncthreads();
    }
    if (idx < n) off[idx] = buf[tid] - v;
    if (tid == 1023) bsum[blockIdx.x] = buf[1023];
}

__global__ __launch_bounds__(64) void scan_carry_kernel(int* __restrict__ bsum,
                                                        int* __restrict__ off,
                                                        int nb, int n)
{
    if (threadIdx.x == 0) {
        int c = 0;
        for (int i = 0; i < nb; ++i) { int t = bsum[i]; bsum[i] = c; c += t; }
        off[n] = c;
    }
}

__global__ __launch_bounds__(1024) void scan_add_kernel(const int* __restrict__ bsum,
                                                        int* __restrict__ off, int n)
{
    int idx = blockIdx.x * 1024 + threadIdx.x;
    if (idx < n) off[idx] += bsum[blockIdx.x];
}

__global__ __launch_bounds__(256) void fill_kernel(const int* __restrict__ coli,
                                                   const int* __restrict__ off,
                                                   int* __restrict__ cursor,
                                                   int* __restrict__ csr)
{
    int e = blockIdx.x * 256 + threadIdx.x;
    if (e < NEDGES) {
        int c = coli[e];
        int pos = atomicAdd(&cursor[c], 1);
        csr[off[c] + pos] = e;
    }
}

// ---------------- per-iteration kernels ----------------

__global__ __launch_bounds__(1024) void prep_kernel(
    const float* __restrict__ y,
    const float* __restrict__ We1, const float* __restrict__ be1,
    const float* __restrict__ Wn1, const float* __restrict__ bn1,
    float* __restrict__ cu_e, float* __restrict__ cu_n,
    float* __restrict__ xagg, float* __restrict__ eagg)
{
    int tid = threadIdx.x;
    if (tid < B_G * FD) xagg[tid] = 0.0f;
    else                eagg[tid - B_G * FD] = 0.0f;

    int g = tid >> 6;
    int j = tid & 63;
    float ae = be1[j];
    float an = bn1[j];
    for (int k = 0; k < FD; ++k) {
        float yv = y[g * FD + k];
        ae = fmaf(yv, We1[(96 + k) * HD + j], ae);
        an = fmaf(yv, Wn1[(64 + k) * HD + j], an);
    }
    cu_e[g * HD + j] = ae;
    cu_n[g * HD + j] = an;
}

// ---- MFMA edge kernel v5: serial-t halves, biases in LDS (low VGPR, NO
//      min-waves launch bound — that spills; see R3/R8), nontemporal ea. ----
__global__ __launch_bounds__(256) void edge_mfma_kernel(
    const unsigned int* __restrict__ x_sp,   // [node][hi16|lo16] dwords
    const float* __restrict__ ea_in,
    const int* __restrict__ rowi,
    const int* __restrict__ coli,
    const unsigned int* __restrict__ wsp,    // E1 @0, E2p @6144
    const float* __restrict__ be2,
    const float* __restrict__ cu_e,
    float* __restrict__ ea_out,
    float* __restrict__ eagg)
{
    __shared__ __align__(16) unsigned int wlds[8192];   // 32 KB weights
    __shared__ __align__(16) float blds[96];            // cu_e[g] (64) + be2 (32)

    const int tid = threadIdx.x;
    const int wid = tid >> 6;
    const int l   = tid & 63;
    const int lm  = l & 15;
    const int lg  = l >> 4;

    const int b   = blockIdx.x;
    const int xcd = b & 7;
    const int i   = b >> 3;
    const int g   = 2 * xcd + (i >> 6);
    const int j0  = i & 63;
    const long gbase = (long)g * EPG;
    const long gend  = gbase + EPG;

    {
        const u32x4* src = (const u32x4*)wsp;
        u32x4* dst = (u32x4*)wlds;
        #pragma unroll
        for (int k = 0; k < 8; ++k)
            dst[tid + k * 256] = src[tid + k * 256];
        if (tid < 64) blds[tid] = cu_e[g * HD + tid];
        else if (tid < 96) blds[tid] = be2[tid - 64];
    }
    __syncthreads();

    f32x4 eacc0 = {0,0,0,0}, eacc1 = {0,0,0,0};

    // one 16-edge half-tile: all static indexing, minimal live state
    auto do_half = [&](long e0, int toff,
                       u32x4 h0, u32x4 l0, u32x4 h1, u32x4 l1,
                       f32x4 v0, f32x4 v1) {
        // acc init from LDS biases (broadcast reads)
        f32x4 acc1[4];
        #pragma unroll
        for (int m = 0; m < 4; ++m)
            acc1[m] = *(const f32x4*)(blds + m * 16 + lg * 4);

        // layer 1, x-src segment (s=0)
        #pragma unroll
        for (int m = 0; m < 4; ++m) {
            bf16x8 wh = ldfrag(wlds + m * 512 + l * 4);
            bf16x8 wl = ldfrag(wlds + m * 512 + 256 + l * 4);
            FragU bh, bl; bh.q = h0; bl.q = l0;
            acc1[m] = mfma16(wh, bh.v, acc1[m]);
            acc1[m] = mfma16(wl, bh.v, acc1[m]);
            acc1[m] = mfma16(wh, bl.v, acc1[m]);
        }
        // layer 1, x-dst segment (s=1)
        #pragma unroll
        for (int m = 0; m < 4; ++m) {
            bf16x8 wh = ldfrag(wlds + (4 + m) * 512 + l * 4);
            bf16x8 wl = ldfrag(wlds + (4 + m) * 512 + 256 + l * 4);
            FragU bh, bl; bh.q = h1; bl.q = l1;
            acc1[m] = mfma16(wh, bh.v, acc1[m]);
            acc1[m] = mfma16(wl, bh.v, acc1[m]);
            acc1[m] = mfma16(wh, bl.v, acc1[m]);
        }
        // layer 1, ea segment (s=2)
        FragU beh, bel;
        fsplit2(v0[0], v0[1], beh.u[0], bel.u[0]);
        fsplit2(v0[2], v0[3], beh.u[1], bel.u[1]);
        fsplit2(v1[0], v1[1], beh.u[2], bel.u[2]);
        fsplit2(v1[2], v1[3], beh.u[3], bel.u[3]);
        #pragma unroll
        for (int m = 0; m < 4; ++m) {
            bf16x8 wh = ldfrag(wlds + (8 + m) * 512 + l * 4);
            bf16x8 wl = ldfrag(wlds + (8 + m) * 512 + 256 + l * 4);
            acc1[m] = mfma16(wh, beh.v, acc1[m]);
            acc1[m] = mfma16(wl, beh.v, acc1[m]);
            acc1[m] = mfma16(wh, bel.v, acc1[m]);
        }

        // B2 frags: relu + split, lane-local (k-order matches permuted W2)
        FragU b2h[2], b2l[2];
        #pragma unroll
        for (int s2 = 0; s2 < 2; ++s2)
            #pragma unroll
            for (int p = 0; p < 4; ++p) {
                int m = 2 * s2 + (p >> 1);
                int r = (2 * p) & 3;
                float a = fmaxf(acc1[m][r], 0.0f);
                float c = fmaxf(acc1[m][r + 1], 0.0f);
                fsplit2(a, c, b2h[s2].u[p], b2l[s2].u[p]);
            }

        // layer 2 (bias from LDS)
        f32x4 acc2[2];
        acc2[0] = *(const f32x4*)(blds + 64 + lg * 4);
        acc2[1] = *(const f32x4*)(blds + 80 + lg * 4);
        #pragma unroll
        for (int s2 = 0; s2 < 2; ++s2)
            #pragma unroll
            for (int n2 = 0; n2 < 2; ++n2) {
                bf16x8 wh = ldfrag(wlds + 6144 + (s2 * 2 + n2) * 512 + l * 4);
                bf16x8 wl = ldfrag(wlds + 6144 + (s2 * 2 + n2) * 512 + 256 + l * 4);
                acc2[n2] = mfma16(wh, b2h[s2].v, acc2[n2]);
                acc2[n2] = mfma16(wl, b2h[s2].v, acc2[n2]);
                acc2[n2] = mfma16(wh, b2l[s2].v, acc2[n2]);
            }

        // store (nontemporal; lane owns edge lm of this half) + eagg accumulate
        int local = toff + lm;
        if (local < (int)(gend - e0)) {
            float* po = ea_out + (e0 + local) * FD + lg * 4;
            __builtin_nontemporal_store(acc2[0], (f32x4*)po);
            __builtin_nontemporal_store(acc2[1], (f32x4*)(po + 16));
            eacc0 += acc2[0];
            eacc1 += acc2[1];
        }
    };

    int nrr[2], ncc[2];
    #pragma unroll
    for (int t = 0; t < 2; ++t) {
        long e = gbase + (long)j0 * 128 + wid * 32 + t * 16 + lm;
        if (e >= gend) e = gend - 1;
        nrr[t] = rowi[e]; ncc[t] = coli[e];
    }

    for (int lt = j0; lt < EDGE_TPG; lt += 64) {
        int rr0 = nrr[0], rr1 = nrr[1], cc0 = ncc[0], cc1 = ncc[1];
        int nlt = lt + 64;
        if (nlt < EDGE_TPG) {
            #pragma unroll
            for (int t = 0; t < 2; ++t) {
                long e = gbase + (long)nlt * 128 + wid * 32 + t * 16 + lm;
                if (e >= gend) e = gend - 1;
                nrr[t] = rowi[e]; ncc[t] = coli[e];
            }
        }
        const long e0 = gbase + (long)lt * 128 + wid * 32;

        // issue ALL gathers for both halves up front
        const unsigned int* pr0 = x_sp + (long)rr0 * 32;
        const unsigned int* pc0 = x_sp + (long)cc0 * 32;
        const unsigned int* pr1 = x_sp + (long)rr1 * 32;
        const unsigned int* pc1 = x_sp + (long)cc1 * 32;
        u32x4 h00 = *(const u32x4*)(pr0 + lg * 4);
        u32x4 l00 = *(const u32x4*)(pr0 + 16 + lg * 4);
        u32x4 h01 = *(const u32x4*)(pc0 + lg * 4);
        u32x4 l01 = *(const u32x4*)(pc0 + 16 + lg * 4);
        u32x4 h10 = *(const u32x4*)(pr1 + lg * 4);
        u32x4 l10 = *(const u32x4*)(pr1 + 16 + lg * 4);
        u32x4 h11 = *(const u32x4*)(pc1 + lg * 4);
        u32x4 l11 = *(const u32x4*)(pc1 + 16 + lg * 4);

        long ee0 = e0 + lm;       if (ee0 >= gend) ee0 = gend - 1;
        long ee1 = e0 + 16 + lm;  if (ee1 >= gend) ee1 = gend - 1;
        const float* pe0 = ea_in + ee0 * FD + lg * 8;
        const float* pe1 = ea_in + ee1 * FD + lg * 8;
        f32x4 v00 = __builtin_nontemporal_load((const f32x4*)pe0);
        f32x4 v01 = __builtin_nontemporal_load((const f32x4*)(pe0 + 4));
        f32x4 v10 = __builtin_nontemporal_load((const f32x4*)pe1);
        f32x4 v11 = __builtin_nontemporal_load((const f32x4*)(pe1 + 4));

        do_half(e0, 0,  h00, l00, h01, l01, v00, v01);
        do_half(e0, 16, h10, l10, h11, l11, v10, v11);
    }

    // eagg: reduce across the 16 lm lanes, one atomic batch per wave
    #pragma unroll
    for (int r = 0; r < 4; ++r) {
        float v0 = eacc0[r], v1 = eacc1[r];
        v0 += __shfl_xor(v0, 1, 64); v1 += __shfl_xor(v1, 1, 64);
        v0 += __shfl_xor(v0, 2, 64); v1 += __shfl_xor(v1, 2, 64);
        v0 += __shfl_xor(v0, 4, 64); v1 += __shfl_xor(v1, 4, 64);
        v0 += __shfl_xor(v0, 8, 64); v1 += __shfl_xor(v1, 8, 64);
        if (lm == 0) {
            atomicAdd(&eagg[g * FD + lg * 4 + r], v0);
            atomicAdd(&eagg[g * FD + 16 + lg * 4 + r], v1);
        }
    }
}

// ---- aggregation: wave per node; 8 rows x 8 feat-quads; nontemporal gather ----
__global__ __launch_bounds__(256) void agg_kernel(
    const float* __restrict__ ea,
    const int* __restrict__ off,
    const int* __restrict__ csr,
    float* __restrict__ e_mean)
{
    int wid = threadIdx.x >> 6;
    int l   = threadIdx.x & 63;
    int rq  = l >> 3;
    int q   = l & 7;
    int n = blockIdx.x * 4 + wid;
    int s0 = off[n], s1 = off[n + 1];
    int deg = s1 - s0;

    f32x4 acc = {0.0f, 0.0f, 0.0f, 0.0f};
    if (deg > 0) {
        int cl = (l < deg) ? l : 0;
        int cidx = csr[s0 + cl];
        #pragma unroll
        for (int r = 0; r < 8; ++r) {
            int src = r * 8 + rq;
            int eid = __shfl(cidx, src, 64);
            if (src < deg) {
                f32x4 v = __builtin_nontemporal_load(
                    (const f32x4*)(ea + (long)eid * FD + q * 4));
                acc += v;
            }
        }
        if (deg > 64) {
            for (int i = s0 + 64; i < s1; i += 8) {
                int ii = i + rq;
                if (ii < s1) {
                    int eid = csr[ii];
                    acc += __builtin_nontemporal_load(
                        (const f32x4*)(ea + (long)eid * FD + q * 4));
                }
            }
        }
    }
    #pragma unroll
    for (int m = 8; m < 64; m <<= 1) {
        acc[0] += __shfl_xor(acc[0], m, 64);
        acc[1] += __shfl_xor(acc[1], m, 64);
        acc[2] += __shfl_xor(acc[2], m, 64);
        acc[3] += __shfl_xor(acc[3], m, 64);
    }
    float inv = 1.0f / (float)(deg > 1 ? deg : 1);
    if (l < 8) {
        f32x4 o = {acc[0] * inv, acc[1] * inv, acc[2] * inv, acc[3] * inv};
        *(f32x4*)(e_mean + (long)n * FD + q * 4) = o;
    }
}

// ---- MFMA node kernel (old structure, unchanged) ----
__global__ __launch_bounds__(256) void node_mfma_kernel(
    const float* __restrict__ x_in,
    const float* __restrict__ e_mean,
    const unsigned int* __restrict__ wsp,  // N1 @0 (rel), N2 @4096 (rel)
    const float* __restrict__ bn2,
    const float* __restrict__ cu_n,
    float* __restrict__ x_out,
    float* __restrict__ xagg)
{
    __shared__ unsigned int h_lds[4][32][68];

    const int tid = threadIdx.x;
    const int wid = tid >> 6;
    const int l   = tid & 63;
    const int lm  = l & 15;
    const int lg  = l >> 4;
    const int koff = lg * 8;

    bf16x8 w1h[2][4], w1l[2][4];
    #pragma unroll
    for (int s = 0; s < 2; ++s)
        #pragma unroll
        for (int n = 0; n < 4; ++n) {
            const unsigned int* p = wsp + (s * 4 + n) * 512 + l * 4;
            w1h[s][n] = ldfrag(p);
            w1l[s][n] = ldfrag(p + 256);
        }
    bf16x8 w2h[2][2], w2l[2][2];
    #pragma unroll
    for (int s = 0; s < 2; ++s)
        #pragma unroll
        for (int n = 0; n < 2; ++n) {
            const unsigned int* p = wsp + 4096 + (s * 2 + n) * 512 + l * 4;
            w2h[s][n] = ldfrag(p);
            w2l[s][n] = ldfrag(p + 256);
        }
    float bias2[2];
    bias2[0] = bn2[lm];
    bias2[1] = bn2[16 + lm];

    const int g  = blockIdx.x / NODE_TPG;
    const int lt = blockIdx.x - g * NODE_TPG;
    const int nb = lt * 128 + wid * 32;

    f32x4 va[2][2][2];
    #pragma unroll
    for (int t = 0; t < 2; ++t) {
        int rl = nb + t * 16 + lm;
        if (rl > NPG - 1) rl = NPG - 1;
        long node = (long)g * NPG + rl;
        const float* p0 = x_in   + node * FD + koff;
        const float* p1 = e_mean + node * FD + koff;
        va[t][0][0] = *(const f32x4*)p0; va[t][0][1] = *(const f32x4*)(p0 + 4);
        va[t][1][0] = *(const f32x4*)p1; va[t][1][1] = *(const f32x4*)(p1 + 4);
    }

    f32x4 acc1[2][4];
    #pragma unroll
    for (int n = 0; n < 4; ++n) {
        float b = cu_n[g * HD + n * 16 + lm];
        #pragma unroll
        for (int t = 0; t < 2; ++t) acc1[t][n] = (f32x4){b, b, b, b};
    }

    #pragma unroll
    for (int t = 0; t < 2; ++t) {
        #pragma unroll
        for (int s = 0; s < 2; ++s) {
            FragU ah, al;
            #pragma unroll
            for (int q = 0; q < 2; ++q)
                #pragma unroll
                for (int p = 0; p < 2; ++p)
                    fsplit2(va[t][s][q][2 * p], va[t][s][q][2 * p + 1],
                            ah.u[q * 2 + p], al.u[q * 2 + p]);
            #pragma unroll
            for (int n = 0; n < 4; ++n) {
                acc1[t][n] = mfma16(ah.v, w1h[s][n], acc1[t][n]);
                acc1[t][n] = mfma16(ah.v, w1l[s][n], acc1[t][n]);
                acc1[t][n] = mfma16(al.v, w1h[s][n], acc1[t][n]);
            }
        }
    }

    #pragma unroll
    for (int t = 0; t < 2; ++t)
        #pragma unroll
        for (int n = 0; n < 4; ++n)
            #pragma unroll
            for (int r = 0; r < 4; ++r)
                h_lds[wid][t * 16 + lg * 4 + r][n * 16 + lm] =
                    fpack_hl(fmaxf(acc1[t][n][r], 0.0f));
    asm volatile("s_waitcnt lgkmcnt(0)" ::: "memory");
    __builtin_amdgcn_sched_barrier(0);

    f32x4 acc2[2][2];
    #pragma unroll
    for (int n = 0; n < 2; ++n) {
        #pragma unroll
        for (int t = 0; t < 2; ++t) acc2[t][n] = (f32x4){bias2[n], bias2[n], bias2[n], bias2[n]};
    }
    #pragma unroll
    for (int t = 0; t < 2; ++t) {
        #pragma unroll
        for (int s = 0; s < 2; ++s) {
            const unsigned int* hp = &h_lds[wid][t * 16 + lm][s * 32 + koff];
            unsigned int u0 = hp[0], u1 = hp[1], u2 = hp[2], u3 = hp[3];
            unsigned int u4 = hp[4], u5 = hp[5], u6 = hp[6], u7 = hp[7];
            FragU ah, al;
            ah.u[0] = __builtin_amdgcn_perm(u1, u0, 0x05040100u);
            ah.u[1] = __builtin_amdgcn_perm(u3, u2, 0x05040100u);
            ah.u[2] = __builtin_amdgcn_perm(u5, u4, 0x05040100u);
            ah.u[3] = __builtin_amdgcn_perm(u7, u6, 0x05040100u);
            al.u[0] = __builtin_amdgcn_perm(u1, u0, 0x07060302u);
            al.u[1] = __builtin_amdgcn_perm(u3, u2, 0x07060302u);
            al.u[2] = __builtin_amdgcn_perm(u5, u4, 0x07060302u);
            al.u[3] = __builtin_amdgcn_perm(u7, u6, 0x07060302u);
            #pragma unroll
            for (int n = 0; n < 2; ++n) {
                acc2[t][n] = mfma16(ah.v, w2h[s][n], acc2[t][n]);
                acc2[t][n] = mfma16(ah.v, w2l[s][n], acc2[t][n]);
                acc2[t][n] = mfma16(al.v, w2h[s][n], acc2[t][n]);
            }
        }
    }

    #pragma unroll
    for (int t = 0; t < 2; ++t)
        #pragma unroll
        for (int r = 0; r < 4; ++r) {
            int rl = nb + t * 16 + lg * 4 + r;
            if (rl < NPG) {
                long node = (long)g * NPG + rl;
                x_out[node * FD + lm]      = acc2[t][0][r];
                x_out[node * FD + 16 + lm] = acc2[t][1][r];
            }
        }

    #pragma unroll
    for (int n = 0; n < 2; ++n) {
        float s = 0.0f;
        #pragma unroll
        for (int t = 0; t < 2; ++t)
            #pragma unroll
            for (int r = 0; r < 4; ++r) {
                int rl = nb + t * 16 + lg * 4 + r;
                s += (rl < NPG) ? acc2[t][n][r] : 0.0f;
            }
        s += __shfl_xor(s, 16, 64);
        s += __shfl_xor(s, 32, 64);
        if (lg == 0) atomicAdd(&xagg[g * FD + n * 16 + lm], s);
    }
}

// ---- global MLP + fused prep + agg zeroing ----
__global__ __launch_bounds__(1024) void global_kernel(
    const float* __restrict__ y_in,
    float* __restrict__ xagg, float* __restrict__ eagg,
    const float* __restrict__ Wg1, const float* __restrict__ bg1,
    const float* __restrict__ Wg2, const float* __restrict__ bg2,
    const float* __restrict__ We1, const float* __restrict__ be1,
    const float* __restrict__ Wn1, const float* __restrict__ bn1,
    float* __restrict__ y_out,
    float* __restrict__ cu_e, float* __restrict__ cu_n)
{
    __shared__ float in_lds[B_G][100];
    __shared__ float h_lds2[B_G][HD + 1];
    __shared__ float y_lds[B_G][FD];
    int tid = threadIdx.x;
    for (int idx = tid; idx < B_G * 96; idx += 1024) {
        int g2 = idx / 96, k = idx % 96;
        float v;
        if (k < 32)      v = xagg[g2 * 32 + k] * (1.0f / NPG);
        else if (k < 64) v = eagg[g2 * 32 + (k - 32)] * (1.0f / EPG);
        else             v = y_in[g2 * 32 + (k - 64)];
        in_lds[g2][k] = v;
    }
    __syncthreads();
    int g = tid >> 6, j = tid & 63;
    float h = bg1[j];
    for (int k = 0; k < 96; ++k)
        h = fmaf(in_lds[g][k], Wg1[k * HD + j], h);
    h_lds2[g][j] = fmaxf(h, 0.0f);
    __syncthreads();
    if (j < FD) {
        float o = bg2[j];
        for (int k = 0; k < HD; ++k)
            o = fmaf(h_lds2[g][k], Wg2[k * FD + j], o);
        y_out[g * FD + j] = o;
        y_lds[g][j] = o;
    }
    __syncthreads();
    float ae = be1[j];
    float an = bn1[j];
    for (int k = 0; k < FD; ++k) {
        float yv = y_lds[g][k];
        ae = fmaf(yv, We1[(96 + k) * HD + j], ae);
        an = fmaf(yv, Wn1[(64 + k) * HD + j], an);
    }
    cu_e[g * HD + j] = ae;
    cu_n[g * HD + j] = an;
    if (tid < B_G * FD)            xagg[tid] = 0.0f;
    else if (tid < 2 * B_G * FD)   eagg[tid - B_G * FD] = 0.0f;
}

// ---------------- launch ----------------

extern "C" void kernel_launch(void* const* d_in, const int* in_sizes, int n_in,
                              void* d_out, int out_size, void* d_ws, size_t ws_size,
                              hipStream_t stream)
{
    const float* x0  = (const float*)d_in[0];
    const float* ea0 = (const float*)d_in[1];
    const float* y0  = (const float*)d_in[2];
    const float* We1 = (const float*)d_in[3];
    const float* be1 = (const float*)d_in[4];
    const float* We2 = (const float*)d_in[5];
    const float* be2 = (const float*)d_in[6];
    const float* Wn1 = (const float*)d_in[7];
    const float* bn1 = (const float*)d_in[8];
    const float* Wn2 = (const float*)d_in[9];
    const float* bn2 = (const float*)d_in[10];
    const float* Wg1 = (const float*)d_in[11];
    const float* bg1 = (const float*)d_in[12];
    const float* Wg2 = (const float*)d_in[13];
    const float* bg2 = (const float*)d_in[14];
    const int*   ei  = (const int*)d_in[15];
    const int* rowi = ei;
    const int* coli = ei + NEDGES;

    float* out_x  = (float*)d_out;
    float* out_ea = out_x + (size_t)NNODES * FD;
    float* out_y  = out_ea + (size_t)NEDGES * FD;

    char* ws = (char*)d_ws;
    int*   off    = (int*)(ws + 0);            // 50001 ints
    int*   cursor = (int*)(ws + 200192);       // 50000 ints
    int*   csr    = (int*)(ws + 400384);       // 800000 ints
    float* xagg   = (float*)(ws + 3600384);    // 16*32
    float* eagg   = xagg + B_G * FD;           // 16*32
    float* cu_e   = (float*)(ws + 3604480);    // 16*64
    float* cu_n   = cu_e + B_G * HD;           // 16*64
    float* e_mean = (float*)(ws + 3612672);    // 6.4 MB
    unsigned int* wsp = (unsigned int*)(ws + 10012672); // 57344 B
    int*   bsum   = (int*)(ws + 10070016);     // 256 B
    unsigned int* x_sp = (unsigned int*)(ws + 10070272); // 6.4 MB

    wsplit_kernel<<<1, 1024, 0, stream>>>(We1, We2, Wn1, Wn2, wsp);
    hipMemsetAsync(cursor, 0, NNODES * sizeof(int), stream);
    count_kernel<<<(NEDGES + 255) / 256, 256, 0, stream>>>(coli, cursor);
    scan_blocks_kernel<<<49, 1024, 0, stream>>>(cursor, off, bsum, NNODES);
    scan_carry_kernel<<<1, 64, 0, stream>>>(bsum, off, 49, NNODES);
    scan_add_kernel<<<49, 1024, 0, stream>>>(bsum, off, NNODES);
    hipMemsetAsync(cursor, 0, NNODES * sizeof(int), stream);
    fill_kernel<<<(NEDGES + 255) / 256, 256, 0, stream>>>(coli, off, cursor, csr);

    prep_kernel<<<1, 1024, 0, stream>>>(y0, We1, be1, Wn1, bn1,
                                        cu_e, cu_n, xagg, eagg);

    for (int it = 0; it < NITER; ++it) {
        const float* xc  = (it == 0) ? x0  : out_x;
        const float* eac = (it == 0) ? ea0 : out_ea;
        const float* yc  = (it == 0) ? y0  : out_y;

        xsplit_kernel<<<(NNODES * 4 + 255) / 256, 256, 0, stream>>>(xc, x_sp);
        edge_mfma_kernel<<<EDGE_BLOCKS, 256, 0, stream>>>(x_sp, eac, rowi, coli,
                                                          wsp, be2, cu_e,
                                                          out_ea, eagg);
        agg_kernel<<<NNODES / 4, 256, 0, stream>>>(out_ea, off, csr, e_mean);
        node_mfma_kernel<<<NODE_BLOCKS, 256, 0, stream>>>(xc, e_mean,
                                                          wsp + 8192, bn2, cu_n,
                                                          out_x, xagg);
        global_kernel<<<1, 1024, 0, stream>>>(yc, xagg, eagg,
                                              Wg1, bg1, Wg2, bg2,
                                              We1, be1, Wn1, bn1,
                                              out_y, cu_e, cu_n);
    }
}

// Round 10
// 703.810 us; speedup vs baseline: 2.2693x; 1.0660x over previous
//
#include <hip/hip_runtime.h>

#define NITER   5
#define B_G     16
#define NPG     3125
#define EPG     50000
#define NNODES  50000
#define NEDGES  800000
#define FD      32
#define HD      64

#define EDGE_TPG   391          // tiles of 128 edges per graph: ceil(50000/128)
#define EDGE_BLOCKS 1024        // 8 XCDs x 128; 64 blocks per graph

#define NODE_TPG   25           // tiles of 128 nodes per graph
#define NODE_BLOCKS (B_G * NODE_TPG)

typedef __attribute__((ext_vector_type(4))) float f32x4;
typedef __attribute__((ext_vector_type(8))) short bf16x8;
typedef __attribute__((ext_vector_type(4))) unsigned int u32x4;

union FragU { bf16x8 v; unsigned int u[4]; u32x4 q; };

// Truncation-based hi/lo split: hi = top16(f), lo = top16(f - hi).
__device__ __forceinline__ void fsplit2(float a, float b,
                                        unsigned int& hi, unsigned int& lo) {
    unsigned int ua = __float_as_uint(a), ub = __float_as_uint(b);
    float la = a - __uint_as_float(ua & 0xffff0000u);
    float lb = b - __uint_as_float(ub & 0xffff0000u);
    hi = __builtin_amdgcn_perm(ub, ua, 0x07060302u);
    lo = __builtin_amdgcn_perm(__float_as_uint(lb), __float_as_uint(la), 0x07060302u);
}
__device__ __forceinline__ unsigned int fpack_hl(float v) {
    unsigned int uv = __float_as_uint(v);
    float lv = v - __uint_as_float(uv & 0xffff0000u);
    return __builtin_amdgcn_perm(__float_as_uint(lv), uv, 0x07060302u);
}
__device__ __forceinline__ bf16x8 ldfrag(const unsigned int* p) {
    FragU t; t.q = *(const u32x4*)p; return t.v;
}
__device__ __forceinline__ f32x4 mfma16(bf16x8 a, bf16x8 b, f32x4 c) {
    return __builtin_amdgcn_mfma_f32_16x16x32_bf16(a, b, c, 0, 0, 0);
}

// ---------------- weight fragment pre-split (once per call) ----------------
// wsp dword layout: E1 (12 frag-pairs) @0, E2-PERMUTED (4) @6144,
//                   N1 (8) @8192, N2 (4) @12288.
__global__ __launch_bounds__(1024) void wsplit_kernel(
    const float* __restrict__ We1, const float* __restrict__ We2,
    const float* __restrict__ Wn1, const float* __restrict__ Wn2,
    unsigned int* __restrict__ wsp)
{
    for (int item = threadIdx.x; item < 1792; item += 1024) {
        int l = item & 63;
        int lm = l & 15, lg = l >> 4;
        if (item < 768) {                       // E1 (A-side W1^T frags)
            int f = item >> 6; int s = f >> 2, n = f & 3;
            unsigned int* dst = wsp + f * 512;
            int rowbase = s * 32 + lg * 8;
            int col = n * 16 + lm;
            #pragma unroll
            for (int p = 0; p < 4; ++p) {
                unsigned int hi, lo;
                fsplit2(We1[(rowbase + 2*p) * HD + col],
                        We1[(rowbase + 2*p + 1) * HD + col], hi, lo);
                dst[l*4 + p] = hi; dst[256 + l*4 + p] = lo;
            }
        } else if (item < 1024) {               // E2 permuted (A-side W2^T, custom k-order)
            int f = (item - 768) >> 6; int s2 = f >> 1, n2 = f & 1;
            unsigned int* dst = wsp + 6144 + f * 512;
            int col = n2 * 16 + lm;
            #pragma unroll
            for (int p = 0; p < 4; ++p) {
                int m  = 2 * s2 + (p >> 1);
                int j0 = m * 16 + lg * 4 + ((2*p) & 3);
                unsigned int hi, lo;
                fsplit2(We2[j0 * FD + col], We2[(j0 + 1) * FD + col], hi, lo);
                dst[l*4 + p] = hi; dst[256 + l*4 + p] = lo;
            }
        } else if (item < 1536) {               // N1 (old layout, node kernel)
            int f = (item - 1024) >> 6; int s = f >> 2, n = f & 3;
            unsigned int* dst = wsp + 8192 + f * 512;
            int rowbase = s * 32 + lg * 8;
            int col = n * 16 + lm;
            #pragma unroll
            for (int p = 0; p < 4; ++p) {
                unsigned int hi, lo;
                fsplit2(Wn1[(rowbase + 2*p) * HD + col],
                        Wn1[(rowbase + 2*p + 1) * HD + col], hi, lo);
                dst[l*4 + p] = hi; dst[256 + l*4 + p] = lo;
            }
        } else {                                // N2 (old layout, node kernel)
            int f = (item - 1536) >> 6; int s = f >> 1, n = f & 1;
            unsigned int* dst = wsp + 12288 + f * 512;
            int rowbase = s * 32 + lg * 8;
            int col = n * 16 + lm;
            #pragma unroll
            for (int p = 0; p < 4; ++p) {
                unsigned int hi, lo;
                fsplit2(Wn2[(rowbase + 2*p) * FD + col],
                        Wn2[(rowbase + 2*p + 1) * FD + col], hi, lo);
                dst[l*4 + p] = hi; dst[256 + l*4 + p] = lo;
            }
        }
    }
}

// ---------------- x pre-split (per iteration): [hi 16dw | lo 16dw] per node ----
__global__ __launch_bounds__(256) void xsplit_kernel(
    const float* __restrict__ xin, unsigned int* __restrict__ x_sp)
{
    int t = blockIdx.x * 256 + threadIdx.x;
    if (t >= NNODES * 4) return;
    int n = t >> 2, c = t & 3;
    long base = (long)n * 32 + c * 8;
    f32x4 a = *(const f32x4*)(xin + base);
    f32x4 b = *(const f32x4*)(xin + base + 4);
    unsigned int h[4], lo[4];
    fsplit2(a[0], a[1], h[0], lo[0]);
    fsplit2(a[2], a[3], h[1], lo[1]);
    fsplit2(b[0], b[1], h[2], lo[2]);
    fsplit2(b[2], b[3], h[3], lo[3]);
    *(u32x4*)(x_sp + (long)n * 32 + c * 4)      = (u32x4){h[0], h[1], h[2], h[3]};
    *(u32x4*)(x_sp + (long)n * 32 + 16 + c * 4) = (u32x4){lo[0], lo[1], lo[2], lo[3]};
}

// ---------------- CSR build (once per call) ----------------

__global__ __launch_bounds__(256) void count_kernel(const int* __restrict__ coli,
                                                    int* __restrict__ cnt)
{
    int e = blockIdx.x * 256 + threadIdx.x;
    if (e < NEDGES) atomicAdd(&cnt[coli[e]], 1);
}

__global__ __launch_bounds__(1024) void scan_blocks_kernel(const int* __restrict__ deg,
                                                           int* __restrict__ off,
                                                           int* __restrict__ bsum, int n)
{
    __shared__ int buf[1024];
    int tid = threadIdx.x;
    int idx = blockIdx.x * 1024 + tid;
    int v = (idx < n) ? deg[idx] : 0;
    buf[tid] = v;
    __syncthreads();
    for (int o = 1; o < 1024; o <<= 1) {
        int t = (tid >= o) ? buf[tid - o] : 0;
        __syncthreads();
        buf[tid] += t;
        __syncthreads();
    }
    if (idx < n) off[idx] = buf[tid] - v;
    if (tid == 1023) bsum[blockIdx.x] = buf[1023];
}

__global__ __launch_bounds__(64) void scan_carry_kernel(int* __restrict__ bsum,
                                                        int* __restrict__ off,
                                                        int nb, int n)
{
    if (threadIdx.x == 0) {
        int c = 0;
        for (int i = 0; i < nb; ++i) { int t = bsum[i]; bsum[i] = c; c += t; }
        off[n] = c;
    }
}

__global__ __launch_bounds__(1024) void scan_add_kernel(const int* __restrict__ bsum,
                                                        int* __restrict__ off, int n)
{
    int idx = blockIdx.x * 1024 + threadIdx.x;
    if (idx < n) off[idx] += bsum[blockIdx.x];
}

__global__ __launch_bounds__(256) void fill_kernel(const int* __restrict__ coli,
                                                   const int* __restrict__ off,
                                                   int* __restrict__ cursor,
                                                   int* __restrict__ csr)
{
    int e = blockIdx.x * 256 + threadIdx.x;
    if (e < NEDGES) {
        int c = coli[e];
        int pos = atomicAdd(&cursor[c], 1);
        csr[off[c] + pos] = e;
    }
}

// ---------------- per-iteration kernels ----------------

__global__ __launch_bounds__(1024) void prep_kernel(
    const float* __restrict__ y,
    const float* __restrict__ We1, const float* __restrict__ be1,
    const float* __restrict__ Wn1, const float* __restrict__ bn1,
    float* __restrict__ cu_e, float* __restrict__ cu_n,
    float* __restrict__ xagg, float* __restrict__ eagg)
{
    int tid = threadIdx.x;
    if (tid < B_G * FD) xagg[tid] = 0.0f;
    else                eagg[tid - B_G * FD] = 0.0f;

    int g = tid >> 6;
    int j = tid & 63;
    float ae = be1[j];
    float an = bn1[j];
    for (int k = 0; k < FD; ++k) {
        float yv = y[g * FD + k];
        ae = fmaf(yv, We1[(96 + k) * HD + j], ae);
        an = fmaf(yv, Wn1[(64 + k) * HD + j], an);
    }
    cu_e[g * HD + j] = ae;
    cu_n[g * HD + j] = an;
}

// ---- MFMA edge kernel v6: shared weight-frag reads across both halves
//      (t-loop inside), biases in LDS, NO min-waves bound, NO nontemporal. ----
__global__ __launch_bounds__(256) void edge_mfma_kernel(
    const unsigned int* __restrict__ x_sp,   // [node][hi16|lo16] dwords
    const float* __restrict__ ea_in,
    const int* __restrict__ rowi,
    const int* __restrict__ coli,
    const unsigned int* __restrict__ wsp,    // E1 @0, E2p @6144
    const float* __restrict__ be2,
    const float* __restrict__ cu_e,
    float* __restrict__ ea_out,
    float* __restrict__ eagg)
{
    __shared__ __align__(16) unsigned int wlds[8192];   // 32 KB weights
    __shared__ __align__(16) float blds[96];            // cu_e[g] (64) + be2 (32)

    const int tid = threadIdx.x;
    const int wid = tid >> 6;
    const int l   = tid & 63;
    const int lm  = l & 15;
    const int lg  = l >> 4;

    const int b   = blockIdx.x;
    const int xcd = b & 7;
    const int i   = b >> 3;
    const int g   = 2 * xcd + (i >> 6);
    const int j0  = i & 63;
    const long gbase = (long)g * EPG;
    const long gend  = gbase + EPG;

    {
        const u32x4* src = (const u32x4*)wsp;
        u32x4* dst = (u32x4*)wlds;
        #pragma unroll
        for (int k = 0; k < 8; ++k)
            dst[tid + k * 256] = src[tid + k * 256];
        if (tid < 64) blds[tid] = cu_e[g * HD + tid];
        else if (tid < 96) blds[tid] = be2[tid - 64];
    }
    __syncthreads();

    f32x4 eacc0 = {0,0,0,0}, eacc1 = {0,0,0,0};

    int nrr[2], ncc[2];
    #pragma unroll
    for (int t = 0; t < 2; ++t) {
        long e = gbase + (long)j0 * 128 + wid * 32 + t * 16 + lm;
        if (e >= gend) e = gend - 1;
        nrr[t] = rowi[e]; ncc[t] = coli[e];
    }

    for (int lt = j0; lt < EDGE_TPG; lt += 64) {
        int rr0 = nrr[0], rr1 = nrr[1], cc0 = ncc[0], cc1 = ncc[1];
        int nlt = lt + 64;
        if (nlt < EDGE_TPG) {
            #pragma unroll
            for (int t = 0; t < 2; ++t) {
                long e = gbase + (long)nlt * 128 + wid * 32 + t * 16 + lm;
                if (e >= gend) e = gend - 1;
                nrr[t] = rowi[e]; ncc[t] = coli[e];
            }
        }
        const long e0 = gbase + (long)lt * 128 + wid * 32;

        // gathers for both halves up front (lane (lm,lg): x[edge=lm][k-octet lg])
        u32x4 xh[2][2], xl[2][2];
        {
            const unsigned int* pr0 = x_sp + (long)rr0 * 32;
            const unsigned int* pc0 = x_sp + (long)cc0 * 32;
            const unsigned int* pr1 = x_sp + (long)rr1 * 32;
            const unsigned int* pc1 = x_sp + (long)cc1 * 32;
            xh[0][0] = *(const u32x4*)(pr0 + lg * 4);
            xl[0][0] = *(const u32x4*)(pr0 + 16 + lg * 4);
            xh[0][1] = *(const u32x4*)(pc0 + lg * 4);
            xl[0][1] = *(const u32x4*)(pc0 + 16 + lg * 4);
            xh[1][0] = *(const u32x4*)(pr1 + lg * 4);
            xl[1][0] = *(const u32x4*)(pr1 + 16 + lg * 4);
            xh[1][1] = *(const u32x4*)(pc1 + lg * 4);
            xl[1][1] = *(const u32x4*)(pc1 + 16 + lg * 4);
        }
        // ea loads (linear)
        f32x4 vea[2][2];
        #pragma unroll
        for (int t = 0; t < 2; ++t) {
            long e = e0 + t * 16 + lm;
            if (e >= gend) e = gend - 1;
            const float* p = ea_in + e * FD + lg * 8;
            vea[t][0] = *(const f32x4*)p;
            vea[t][1] = *(const f32x4*)(p + 4);
        }

        // acc init from LDS biases (broadcast reads)
        f32x4 acc1[2][4];
        #pragma unroll
        for (int m = 0; m < 4; ++m) {
            f32x4 bb = *(const f32x4*)(blds + m * 16 + lg * 4);
            acc1[0][m] = bb; acc1[1][m] = bb;
        }

        // layer 1, x segments: each weight frag read ONCE, used by both halves
        #pragma unroll
        for (int s = 0; s < 2; ++s)
            #pragma unroll
            for (int m = 0; m < 4; ++m) {
                bf16x8 wh = ldfrag(wlds + (s * 4 + m) * 512 + l * 4);
                bf16x8 wl = ldfrag(wlds + (s * 4 + m) * 512 + 256 + l * 4);
                #pragma unroll
                for (int t = 0; t < 2; ++t) {
                    FragU bh, bl; bh.q = xh[t][s]; bl.q = xl[t][s];
                    acc1[t][m] = mfma16(wh, bh.v, acc1[t][m]);
                    acc1[t][m] = mfma16(wl, bh.v, acc1[t][m]);
                    acc1[t][m] = mfma16(wh, bl.v, acc1[t][m]);
                }
            }
        // layer 1, ea segment
        FragU beh[2], bel[2];
        #pragma unroll
        for (int t = 0; t < 2; ++t) {
            fsplit2(vea[t][0][0], vea[t][0][1], beh[t].u[0], bel[t].u[0]);
            fsplit2(vea[t][0][2], vea[t][0][3], beh[t].u[1], bel[t].u[1]);
            fsplit2(vea[t][1][0], vea[t][1][1], beh[t].u[2], bel[t].u[2]);
            fsplit2(vea[t][1][2], vea[t][1][3], beh[t].u[3], bel[t].u[3]);
        }
        #pragma unroll
        for (int m = 0; m < 4; ++m) {
            bf16x8 wh = ldfrag(wlds + (8 + m) * 512 + l * 4);
            bf16x8 wl = ldfrag(wlds + (8 + m) * 512 + 256 + l * 4);
            #pragma unroll
            for (int t = 0; t < 2; ++t) {
                acc1[t][m] = mfma16(wh, beh[t].v, acc1[t][m]);
                acc1[t][m] = mfma16(wl, beh[t].v, acc1[t][m]);
                acc1[t][m] = mfma16(wh, bel[t].v, acc1[t][m]);
            }
        }

        // B2 frags: relu + split, lane-local (k-order matches permuted W2)
        FragU b2h[2][2], b2l[2][2];
        #pragma unroll
        for (int t = 0; t < 2; ++t)
            #pragma unroll
            for (int s2 = 0; s2 < 2; ++s2)
                #pragma unroll
                for (int p = 0; p < 4; ++p) {
                    int m = 2 * s2 + (p >> 1);
                    int r = (2 * p) & 3;
                    float a = fmaxf(acc1[t][m][r], 0.0f);
                    float c = fmaxf(acc1[t][m][r + 1], 0.0f);
                    fsplit2(a, c, b2h[t][s2].u[p], b2l[t][s2].u[p]);
                }

        // layer 2 (bias from LDS; weight frags read once, both halves)
        f32x4 acc2[2][2];
        {
            f32x4 b20 = *(const f32x4*)(blds + 64 + lg * 4);
            f32x4 b21 = *(const f32x4*)(blds + 80 + lg * 4);
            acc2[0][0] = b20; acc2[1][0] = b20;
            acc2[0][1] = b21; acc2[1][1] = b21;
        }
        #pragma unroll
        for (int s2 = 0; s2 < 2; ++s2)
            #pragma unroll
            for (int n2 = 0; n2 < 2; ++n2) {
                bf16x8 wh = ldfrag(wlds + 6144 + (s2 * 2 + n2) * 512 + l * 4);
                bf16x8 wl = ldfrag(wlds + 6144 + (s2 * 2 + n2) * 512 + 256 + l * 4);
                #pragma unroll
                for (int t = 0; t < 2; ++t) {
                    acc2[t][n2] = mfma16(wh, b2h[t][s2].v, acc2[t][n2]);
                    acc2[t][n2] = mfma16(wl, b2h[t][s2].v, acc2[t][n2]);
                    acc2[t][n2] = mfma16(wh, b2l[t][s2].v, acc2[t][n2]);
                }
            }

        // store (lane owns edge lm of each half) + eagg register accumulate
        int cnt = (int)(gend - e0);
        #pragma unroll
        for (int t = 0; t < 2; ++t) {
            int local = t * 16 + lm;
            if (local < cnt) {
                float* po = ea_out + (e0 + local) * FD + lg * 4;
                *(f32x4*)po        = acc2[t][0];
                *(f32x4*)(po + 16) = acc2[t][1];
                eacc0 += acc2[t][0];
                eacc1 += acc2[t][1];
            }
        }
    }

    // eagg: reduce across the 16 lm lanes, one atomic batch per wave
    #pragma unroll
    for (int r = 0; r < 4; ++r) {
        float v0 = eacc0[r], v1 = eacc1[r];
        v0 += __shfl_xor(v0, 1, 64); v1 += __shfl_xor(v1, 1, 64);
        v0 += __shfl_xor(v0, 2, 64); v1 += __shfl_xor(v1, 2, 64);
        v0 += __shfl_xor(v0, 4, 64); v1 += __shfl_xor(v1, 4, 64);
        v0 += __shfl_xor(v0, 8, 64); v1 += __shfl_xor(v1, 8, 64);
        if (lm == 0) {
            atomicAdd(&eagg[g * FD + lg * 4 + r], v0);
            atomicAdd(&eagg[g * FD + 16 + lg * 4 + r], v1);
        }
    }
}

// ---- aggregation: wave per node; 8 rows x 8 feat-quads (no NT — L2 reuse) ----
__global__ __launch_bounds__(256) void agg_kernel(
    const float* __restrict__ ea,
    const int* __restrict__ off,
    const int* __restrict__ csr,
    float* __restrict__ e_mean)
{
    int wid = threadIdx.x >> 6;
    int l   = threadIdx.x & 63;
    int rq  = l >> 3;
    int q   = l & 7;
    int n = blockIdx.x * 4 + wid;
    int s0 = off[n], s1 = off[n + 1];
    int deg = s1 - s0;

    f32x4 acc = {0.0f, 0.0f, 0.0f, 0.0f};
    if (deg > 0) {
        int cl = (l < deg) ? l : 0;
        int cidx = csr[s0 + cl];
        #pragma unroll
        for (int r = 0; r < 8; ++r) {
            int src = r * 8 + rq;
            int eid = __shfl(cidx, src, 64);
            if (src < deg) {
                f32x4 v = *(const f32x4*)(ea + (long)eid * FD + q * 4);
                acc += v;
            }
        }
        if (deg > 64) {
            for (int i = s0 + 64; i < s1; i += 8) {
                int ii = i + rq;
                if (ii < s1) {
                    int eid = csr[ii];
                    acc += *(const f32x4*)(ea + (long)eid * FD + q * 4);
                }
            }
        }
    }
    #pragma unroll
    for (int m = 8; m < 64; m <<= 1) {
        acc[0] += __shfl_xor(acc[0], m, 64);
        acc[1] += __shfl_xor(acc[1], m, 64);
        acc[2] += __shfl_xor(acc[2], m, 64);
        acc[3] += __shfl_xor(acc[3], m, 64);
    }
    float inv = 1.0f / (float)(deg > 1 ? deg : 1);
    if (l < 8) {
        f32x4 o = {acc[0] * inv, acc[1] * inv, acc[2] * inv, acc[3] * inv};
        *(f32x4*)(e_mean + (long)n * FD + q * 4) = o;
    }
}

// ---- MFMA node kernel (old structure, unchanged) ----
__global__ __launch_bounds__(256) void node_mfma_kernel(
    const float* __restrict__ x_in,
    const float* __restrict__ e_mean,
    const unsigned int* __restrict__ wsp,  // N1 @0 (rel), N2 @4096 (rel)
    const float* __restrict__ bn2,
    const float* __restrict__ cu_n,
    float* __restrict__ x_out,
    float* __restrict__ xagg)
{
    __shared__ unsigned int h_lds[4][32][68];

    const int tid = threadIdx.x;
    const int wid = tid >> 6;
    const int l   = tid & 63;
    const int lm  = l & 15;
    const int lg  = l >> 4;
    const int koff = lg * 8;

    bf16x8 w1h[2][4], w1l[2][4];
    #pragma unroll
    for (int s = 0; s < 2; ++s)
        #pragma unroll
        for (int n = 0; n < 4; ++n) {
            const unsigned int* p = wsp + (s * 4 + n) * 512 + l * 4;
            w1h[s][n] = ldfrag(p);
            w1l[s][n] = ldfrag(p + 256);
        }
    bf16x8 w2h[2][2], w2l[2][2];
    #pragma unroll
    for (int s = 0; s < 2; ++s)
        #pragma unroll
        for (int n = 0; n < 2; ++n) {
            const unsigned int* p = wsp + 4096 + (s * 2 + n) * 512 + l * 4;
            w2h[s][n] = ldfrag(p);
            w2l[s][n] = ldfrag(p + 256);
        }
    float bias2[2];
    bias2[0] = bn2[lm];
    bias2[1] = bn2[16 + lm];

    const int g  = blockIdx.x / NODE_TPG;
    const int lt = blockIdx.x - g * NODE_TPG;
    const int nb = lt * 128 + wid * 32;

    f32x4 va[2][2][2];
    #pragma unroll
    for (int t = 0; t < 2; ++t) {
        int rl = nb + t * 16 + lm;
        if (rl > NPG - 1) rl = NPG - 1;
        long node = (long)g * NPG + rl;
        const float* p0 = x_in   + node * FD + koff;
        const float* p1 = e_mean + node * FD + koff;
        va[t][0][0] = *(const f32x4*)p0; va[t][0][1] = *(const f32x4*)(p0 + 4);
        va[t][1][0] = *(const f32x4*)p1; va[t][1][1] = *(const f32x4*)(p1 + 4);
    }

    f32x4 acc1[2][4];
    #pragma unroll
    for (int n = 0; n < 4; ++n) {
        float b = cu_n[g * HD + n * 16 + lm];
        #pragma unroll
        for (int t = 0; t < 2; ++t) acc1[t][n] = (f32x4){b, b, b, b};
    }

    #pragma unroll
    for (int t = 0; t < 2; ++t) {
        #pragma unroll
        for (int s = 0; s < 2; ++s) {
            FragU ah, al;
            #pragma unroll
            for (int q = 0; q < 2; ++q)
                #pragma unroll
                for (int p = 0; p < 2; ++p)
                    fsplit2(va[t][s][q][2 * p], va[t][s][q][2 * p + 1],
                            ah.u[q * 2 + p], al.u[q * 2 + p]);
            #pragma unroll
            for (int n = 0; n < 4; ++n) {
                acc1[t][n] = mfma16(ah.v, w1h[s][n], acc1[t][n]);
                acc1[t][n] = mfma16(ah.v, w1l[s][n], acc1[t][n]);
                acc1[t][n] = mfma16(al.v, w1h[s][n], acc1[t][n]);
            }
        }
    }

    #pragma unroll
    for (int t = 0; t < 2; ++t)
        #pragma unroll
        for (int n = 0; n < 4; ++n)
            #pragma unroll
            for (int r = 0; r < 4; ++r)
                h_lds[wid][t * 16 + lg * 4 + r][n * 16 + lm] =
                    fpack_hl(fmaxf(acc1[t][n][r], 0.0f));
    asm volatile("s_waitcnt lgkmcnt(0)" ::: "memory");
    __builtin_amdgcn_sched_barrier(0);

    f32x4 acc2[2][2];
    #pragma unroll
    for (int n = 0; n < 2; ++n) {
        #pragma unroll
        for (int t = 0; t < 2; ++t) acc2[t][n] = (f32x4){bias2[n], bias2[n], bias2[n], bias2[n]};
    }
    #pragma unroll
    for (int t = 0; t < 2; ++t) {
        #pragma unroll
        for (int s = 0; s < 2; ++s) {
            const unsigned int* hp = &h_lds[wid][t * 16 + lm][s * 32 + koff];
            unsigned int u0 = hp[0], u1 = hp[1], u2 = hp[2], u3 = hp[3];
            unsigned int u4 = hp[4], u5 = hp[5], u6 = hp[6], u7 = hp[7];
            FragU ah, al;
            ah.u[0] = __builtin_amdgcn_perm(u1, u0, 0x05040100u);
            ah.u[1] = __builtin_amdgcn_perm(u3, u2, 0x05040100u);
            ah.u[2] = __builtin_amdgcn_perm(u5, u4, 0x05040100u);
            ah.u[3] = __builtin_amdgcn_perm(u7, u6, 0x05040100u);
            al.u[0] = __builtin_amdgcn_perm(u1, u0, 0x07060302u);
            al.u[1] = __builtin_amdgcn_perm(u3, u2, 0x07060302u);
            al.u[2] = __builtin_amdgcn_perm(u5, u4, 0x07060302u);
            al.u[3] = __builtin_amdgcn_perm(u7, u6, 0x07060302u);
            #pragma unroll
            for (int n = 0; n < 2; ++n) {
                acc2[t][n] = mfma16(ah.v, w2h[s][n], acc2[t][n]);
                acc2[t][n] = mfma16(ah.v, w2l[s][n], acc2[t][n]);
                acc2[t][n] = mfma16(al.v, w2h[s][n], acc2[t][n]);
            }
        }
    }

    #pragma unroll
    for (int t = 0; t < 2; ++t)
        #pragma unroll
        for (int r = 0; r < 4; ++r) {
            int rl = nb + t * 16 + lg * 4 + r;
            if (rl < NPG) {
                long node = (long)g * NPG + rl;
                x_out[node * FD + lm]      = acc2[t][0][r];
                x_out[node * FD + 16 + lm] = acc2[t][1][r];
            }
        }

    #pragma unroll
    for (int n = 0; n < 2; ++n) {
        float s = 0.0f;
        #pragma unroll
        for (int t = 0; t < 2; ++t)
            #pragma unroll
            for (int r = 0; r < 4; ++r) {
                int rl = nb + t * 16 + lg * 4 + r;
                s += (rl < NPG) ? acc2[t][n][r] : 0.0f;
            }
        s += __shfl_xor(s, 16, 64);
        s += __shfl_xor(s, 32, 64);
        if (lg == 0) atomicAdd(&xagg[g * FD + n * 16 + lm], s);
    }
}

// ---- global MLP + fused prep + agg zeroing ----
__global__ __launch_bounds__(1024) void global_kernel(
    const float* __restrict__ y_in,
    float* __restrict__ xagg, float* __restrict__ eagg,
    const float* __restrict__ Wg1, const float* __restrict__ bg1,
    const float* __restrict__ Wg2, const float* __restrict__ bg2,
    const float* __restrict__ We1, const float* __restrict__ be1,
    const float* __restrict__ Wn1, const float* __restrict__ bn1,
    float* __restrict__ y_out,
    float* __restrict__ cu_e, float* __restrict__ cu_n)
{
    __shared__ float in_lds[B_G][100];
    __shared__ float h_lds2[B_G][HD + 1];
    __shared__ float y_lds[B_G][FD];
    int tid = threadIdx.x;
    for (int idx = tid; idx < B_G * 96; idx += 1024) {
        int g2 = idx / 96, k = idx % 96;
        float v;
        if (k < 32)      v = xagg[g2 * 32 + k] * (1.0f / NPG);
        else if (k < 64) v = eagg[g2 * 32 + (k - 32)] * (1.0f / EPG);
        else             v = y_in[g2 * 32 + (k - 64)];
        in_lds[g2][k] = v;
    }
    __syncthreads();
    int g = tid >> 6, j = tid & 63;
    float h = bg1[j];
    for (int k = 0; k < 96; ++k)
        h = fmaf(in_lds[g][k], Wg1[k * HD + j], h);
    h_lds2[g][j] = fmaxf(h, 0.0f);
    __syncthreads();
    if (j < FD) {
        float o = bg2[j];
        for (int k = 0; k < HD; ++k)
            o = fmaf(h_lds2[g][k], Wg2[k * FD + j], o);
        y_out[g * FD + j] = o;
        y_lds[g][j] = o;
    }
    __syncthreads();
    float ae = be1[j];
    float an = bn1[j];
    for (int k = 0; k < FD; ++k) {
        float yv = y_lds[g][k];
        ae = fmaf(yv, We1[(96 + k) * HD + j], ae);
        an = fmaf(yv, Wn1[(64 + k) * HD + j], an);
    }
    cu_e[g * HD + j] = ae;
    cu_n[g * HD + j] = an;
    if (tid < B_G * FD)            xagg[tid] = 0.0f;
    else if (tid < 2 * B_G * FD)   eagg[tid - B_G * FD] = 0.0f;
}

// ---------------- launch ----------------

extern "C" void kernel_launch(void* const* d_in, const int* in_sizes, int n_in,
                              void* d_out, int out_size, void* d_ws, size_t ws_size,
                              hipStream_t stream)
{
    const float* x0  = (const float*)d_in[0];
    const float* ea0 = (const float*)d_in[1];
    const float* y0  = (const float*)d_in[2];
    const float* We1 = (const float*)d_in[3];
    const float* be1 = (const float*)d_in[4];
    const float* We2 = (const float*)d_in[5];
    const float* be2 = (const float*)d_in[6];
    const float* Wn1 = (const float*)d_in[7];
    const float* bn1 = (const float*)d_in[8];
    const float* Wn2 = (const float*)d_in[9];
    const float* bn2 = (const float*)d_in[10];
    const float* Wg1 = (const float*)d_in[11];
    const float* bg1 = (const float*)d_in[12];
    const float* Wg2 = (const float*)d_in[13];
    const float* bg2 = (const float*)d_in[14];
    const int*   ei  = (const int*)d_in[15];
    const int* rowi = ei;
    const int* coli = ei + NEDGES;

    float* out_x  = (float*)d_out;
    float* out_ea = out_x + (size_t)NNODES * FD;
    float* out_y  = out_ea + (size_t)NEDGES * FD;

    char* ws = (char*)d_ws;
    int*   off    = (int*)(ws + 0);            // 50001 ints
    int*   cursor = (int*)(ws + 200192);       // 50000 ints
    int*   csr    = (int*)(ws + 400384);       // 800000 ints
    float* xagg   = (float*)(ws + 3600384);    // 16*32
    float* eagg   = xagg + B_G * FD;           // 16*32
    float* cu_e   = (float*)(ws + 3604480);    // 16*64
    float* cu_n   = cu_e + B_G * HD;           // 16*64
    float* e_mean = (float*)(ws + 3612672);    // 6.4 MB
    unsigned int* wsp = (unsigned int*)(ws + 10012672); // 57344 B
    int*   bsum   = (int*)(ws + 10070016);     // 256 B
    unsigned int* x_sp = (unsigned int*)(ws + 10070272); // 6.4 MB

    wsplit_kernel<<<1, 1024, 0, stream>>>(We1, We2, Wn1, Wn2, wsp);
    hipMemsetAsync(cursor, 0, NNODES * sizeof(int), stream);
    count_kernel<<<(NEDGES + 255) / 256, 256, 0, stream>>>(coli, cursor);
    scan_blocks_kernel<<<49, 1024, 0, stream>>>(cursor, off, bsum, NNODES);
    scan_carry_kernel<<<1, 64, 0, stream>>>(bsum, off, 49, NNODES);
    scan_add_kernel<<<49, 1024, 0, stream>>>(bsum, off, NNODES);
    hipMemsetAsync(cursor, 0, NNODES * sizeof(int), stream);
    fill_kernel<<<(NEDGES + 255) / 256, 256, 0, stream>>>(coli, off, cursor, csr);

    prep_kernel<<<1, 1024, 0, stream>>>(y0, We1, be1, Wn1, bn1,
                                        cu_e, cu_n, xagg, eagg);

    for (int it = 0; it < NITER; ++it) {
        const float* xc  = (it == 0) ? x0  : out_x;
        const float* eac = (it == 0) ? ea0 : out_ea;
        const float* yc  = (it == 0) ? y0  : out_y;

        xsplit_kernel<<<(NNODES * 4 + 255) / 256, 256, 0, stream>>>(xc, x_sp);
        edge_mfma_kernel<<<EDGE_BLOCKS, 256, 0, stream>>>(x_sp, eac, rowi, coli,
                                                          wsp, be2, cu_e,
                                                          out_ea, eagg);
        agg_kernel<<<NNODES / 4, 256, 0, stream>>>(out_ea, off, csr, e_mean);
        node_mfma_kernel<<<NODE_BLOCKS, 256, 0, stream>>>(xc, e_mean,
                                                          wsp + 8192, bn2, cu_n,
                                                          out_x, xagg);
        global_kernel<<<1, 1024, 0, stream>>>(yc, xagg, eagg,
                                              Wg1, bg1, Wg2, bg2,
                                              We1, be1, Wn1, bn1,
                                              out_y, cu_e, cu_n);
    }
}

// Round 11
// 640.917 us; speedup vs baseline: 2.4920x; 1.0981x over previous
//
#include <hip/hip_runtime.h>

#define NITER   5
#define B_G     16
#define NPG     3125
#define EPG     50000
#define NNODES  50000
#define NEDGES  800000
#define FD      32
#define HD      64

#define EDGE_TPG   391          // tiles of 128 edges per graph: ceil(50000/128)
#define EDGE_BLOCKS 1024        // 8 XCDs x 128; 64 blocks per graph

#define NODE_TPG   25           // tiles of 128 nodes per graph
#define NODE_BLOCKS (B_G * NODE_TPG)

typedef __attribute__((ext_vector_type(4))) float f32x4;
typedef __attribute__((ext_vector_type(8))) short bf16x8;
typedef __attribute__((ext_vector_type(4))) unsigned int u32x4;

union FragU { bf16x8 v; unsigned int u[4]; u32x4 q; };

// Truncation-based hi/lo split: hi = top16(f), lo = top16(f - hi).
__device__ __forceinline__ void fsplit2(float a, float b,
                                        unsigned int& hi, unsigned int& lo) {
    unsigned int ua = __float_as_uint(a), ub = __float_as_uint(b);
    float la = a - __uint_as_float(ua & 0xffff0000u);
    float lb = b - __uint_as_float(ub & 0xffff0000u);
    hi = __builtin_amdgcn_perm(ub, ua, 0x07060302u);
    lo = __builtin_amdgcn_perm(__float_as_uint(lb), __float_as_uint(la), 0x07060302u);
}
__device__ __forceinline__ unsigned int fpack_hl(float v) {
    unsigned int uv = __float_as_uint(v);
    float lv = v - __uint_as_float(uv & 0xffff0000u);
    return __builtin_amdgcn_perm(__float_as_uint(lv), uv, 0x07060302u);
}
__device__ __forceinline__ bf16x8 ldfrag(const unsigned int* p) {
    FragU t; t.q = *(const u32x4*)p; return t.v;
}
__device__ __forceinline__ f32x4 mfma16(bf16x8 a, bf16x8 b, f32x4 c) {
    return __builtin_amdgcn_mfma_f32_16x16x32_bf16(a, b, c, 0, 0, 0);
}

// ---------------- weight fragment pre-split (once per call) ----------------
// wsp dword layout: E1 (12 frag-pairs) @0, E2-PERMUTED (4) @6144,
//                   N1 (8) @8192, N2 (4) @12288.
__global__ __launch_bounds__(1024) void wsplit_kernel(
    const float* __restrict__ We1, const float* __restrict__ We2,
    const float* __restrict__ Wn1, const float* __restrict__ Wn2,
    unsigned int* __restrict__ wsp)
{
    for (int item = threadIdx.x; item < 1792; item += 1024) {
        int l = item & 63;
        int lm = l & 15, lg = l >> 4;
        if (item < 768) {                       // E1 (A-side W1^T frags)
            int f = item >> 6; int s = f >> 2, n = f & 3;
            unsigned int* dst = wsp + f * 512;
            int rowbase = s * 32 + lg * 8;
            int col = n * 16 + lm;
            #pragma unroll
            for (int p = 0; p < 4; ++p) {
                unsigned int hi, lo;
                fsplit2(We1[(rowbase + 2*p) * HD + col],
                        We1[(rowbase + 2*p + 1) * HD + col], hi, lo);
                dst[l*4 + p] = hi; dst[256 + l*4 + p] = lo;
            }
        } else if (item < 1024) {               // E2 permuted (A-side W2^T, custom k-order)
            int f = (item - 768) >> 6; int s2 = f >> 1, n2 = f & 1;
            unsigned int* dst = wsp + 6144 + f * 512;
            int col = n2 * 16 + lm;
            #pragma unroll
            for (int p = 0; p < 4; ++p) {
                int m  = 2 * s2 + (p >> 1);
                int j0 = m * 16 + lg * 4 + ((2*p) & 3);
                unsigned int hi, lo;
                fsplit2(We2[j0 * FD + col], We2[(j0 + 1) * FD + col], hi, lo);
                dst[l*4 + p] = hi; dst[256 + l*4 + p] = lo;
            }
        } else if (item < 1536) {               // N1 (old layout, node kernel)
            int f = (item - 1024) >> 6; int s = f >> 2, n = f & 3;
            unsigned int* dst = wsp + 8192 + f * 512;
            int rowbase = s * 32 + lg * 8;
            int col = n * 16 + lm;
            #pragma unroll
            for (int p = 0; p < 4; ++p) {
                unsigned int hi, lo;
                fsplit2(Wn1[(rowbase + 2*p) * HD + col],
                        Wn1[(rowbase + 2*p + 1) * HD + col], hi, lo);
                dst[l*4 + p] = hi; dst[256 + l*4 + p] = lo;
            }
        } else {                                // N2 (old layout, node kernel)
            int f = (item - 1536) >> 6; int s = f >> 1, n = f & 1;
            unsigned int* dst = wsp + 12288 + f * 512;
            int rowbase = s * 32 + lg * 8;
            int col = n * 16 + lm;
            #pragma unroll
            for (int p = 0; p < 4; ++p) {
                unsigned int hi, lo;
                fsplit2(Wn2[(rowbase + 2*p) * FD + col],
                        Wn2[(rowbase + 2*p + 1) * FD + col], hi, lo);
                dst[l*4 + p] = hi; dst[256 + l*4 + p] = lo;
            }
        }
    }
}

// ---------------- x pre-split (per iteration): [hi 16dw | lo 16dw] per node ----
__global__ __launch_bounds__(256) void xsplit_kernel(
    const float* __restrict__ xin, unsigned int* __restrict__ x_sp)
{
    int t = blockIdx.x * 256 + threadIdx.x;
    if (t >= NNODES * 4) return;
    int n = t >> 2, c = t & 3;
    long base = (long)n * 32 + c * 8;
    f32x4 a = *(const f32x4*)(xin + base);
    f32x4 b = *(const f32x4*)(xin + base + 4);
    unsigned int h[4], lo[4];
    fsplit2(a[0], a[1], h[0], lo[0]);
    fsplit2(a[2], a[3], h[1], lo[1]);
    fsplit2(b[0], b[1], h[2], lo[2]);
    fsplit2(b[2], b[3], h[3], lo[3]);
    *(u32x4*)(x_sp + (long)n * 32 + c * 4)      = (u32x4){h[0], h[1], h[2], h[3]};
    *(u32x4*)(x_sp + (long)n * 32 + 16 + c * 4) = (u32x4){lo[0], lo[1], lo[2], lo[3]};
}

// ---------------- CSR build (once per call) ----------------

__global__ __launch_bounds__(256) void count_kernel(const int* __restrict__ coli,
                                                    int* __restrict__ cnt)
{
    int e = blockIdx.x * 256 + threadIdx.x;
    if (e < NEDGES) atomicAdd(&cnt[coli[e]], 1);
}

__global__ __launch_bounds__(1024) void scan_blocks_kernel(const int* __restrict__ deg,
                                                           int* __restrict__ off,
                                                           int* __restrict__ bsum, int n)
{
    __shared__ int buf[1024];
    int tid = threadIdx.x;
    int idx = blockIdx.x * 1024 + tid;
    int v = (idx < n) ? deg[idx] : 0;
    buf[tid] = v;
    __syncthreads();
    for (int o = 1; o < 1024; o <<= 1) {
        int t = (tid >= o) ? buf[tid - o] : 0;
        __syncthreads();
        buf[tid] += t;
        __syncthreads();
    }
    if (idx < n) off[idx] = buf[tid] - v;
    if (tid == 1023) bsum[blockIdx.x] = buf[1023];
}

__global__ __launch_bounds__(64) void scan_carry_kernel(int* __restrict__ bsum,
                                                        int* __restrict__ off,
                                                        int nb, int n)
{
    if (threadIdx.x == 0) {
        int c = 0;
        for (int i = 0; i < nb; ++i) { int t = bsum[i]; bsum[i] = c; c += t; }
        off[n] = c;
    }
}

__global__ __launch_bounds__(1024) void scan_add_kernel(const int* __restrict__ bsum,
                                                        int* __restrict__ off, int n)
{
    int idx = blockIdx.x * 1024 + threadIdx.x;
    if (idx < n) off[idx] += bsum[blockIdx.x];
}

__global__ __launch_bounds__(256) void fill_kernel(const int* __restrict__ coli,
                                                   const int* __restrict__ off,
                                                   int* __restrict__ cursor,
                                                   int* __restrict__ csr)
{
    int e = blockIdx.x * 256 + threadIdx.x;
    if (e < NEDGES) {
        int c = coli[e];
        int pos = atomicAdd(&cursor[c], 1);
        csr[off[c] + pos] = e;
    }
}

// ---------------- per-iteration kernels ----------------

__global__ __launch_bounds__(1024) void prep_kernel(
    const float* __restrict__ y,
    const float* __restrict__ We1, const float* __restrict__ be1,
    const float* __restrict__ Wn1, const float* __restrict__ bn1,
    float* __restrict__ cu_e, float* __restrict__ cu_n,
    float* __restrict__ xagg, float* __restrict__ eagg)
{
    int tid = threadIdx.x;
    if (tid < B_G * FD) xagg[tid] = 0.0f;
    else                eagg[tid - B_G * FD] = 0.0f;

    int g = tid >> 6;
    int j = tid & 63;
    float ae = be1[j];
    float an = bn1[j];
    for (int k = 0; k < FD; ++k) {
        float yv = y[g * FD + k];
        ae = fmaf(yv, We1[(96 + k) * HD + j], ae);
        an = fmaf(yv, Wn1[(64 + k) * HD + j], an);
    }
    cu_e[g * HD + j] = ae;
    cu_n[g * HD + j] = an;
}

// ---- MFMA edge kernel (R9 structure): serial halves, per-half weight reads
//      from LDS, biases in LDS, NO min-waves bound, NO nontemporal. ----
__global__ __launch_bounds__(256) void edge_mfma_kernel(
    const unsigned int* __restrict__ x_sp,   // [node][hi16|lo16] dwords
    const float* __restrict__ ea_in,
    const int* __restrict__ rowi,
    const int* __restrict__ coli,
    const unsigned int* __restrict__ wsp,    // E1 @0, E2p @6144
    const float* __restrict__ be2,
    const float* __restrict__ cu_e,
    float* __restrict__ ea_out,
    float* __restrict__ eagg)
{
    __shared__ __align__(16) unsigned int wlds[8192];   // 32 KB weights
    __shared__ __align__(16) float blds[96];            // cu_e[g] (64) + be2 (32)

    const int tid = threadIdx.x;
    const int wid = tid >> 6;
    const int l   = tid & 63;
    const int lm  = l & 15;
    const int lg  = l >> 4;

    const int b   = blockIdx.x;
    const int xcd = b & 7;
    const int i   = b >> 3;
    const int g   = 2 * xcd + (i >> 6);
    const int j0  = i & 63;
    const long gbase = (long)g * EPG;
    const long gend  = gbase + EPG;

    {
        const u32x4* src = (const u32x4*)wsp;
        u32x4* dst = (u32x4*)wlds;
        #pragma unroll
        for (int k = 0; k < 8; ++k)
            dst[tid + k * 256] = src[tid + k * 256];
        if (tid < 64) blds[tid] = cu_e[g * HD + tid];
        else if (tid < 96) blds[tid] = be2[tid - 64];
    }
    __syncthreads();

    f32x4 eacc0 = {0,0,0,0}, eacc1 = {0,0,0,0};

    // one 16-edge half-tile: all static indexing, minimal live state
    auto do_half = [&](long e0, int toff,
                       u32x4 h0, u32x4 l0, u32x4 h1, u32x4 l1,
                       f32x4 v0, f32x4 v1) {
        // acc init from LDS biases (broadcast reads)
        f32x4 acc1[4];
        #pragma unroll
        for (int m = 0; m < 4; ++m)
            acc1[m] = *(const f32x4*)(blds + m * 16 + lg * 4);

        // layer 1, x-src segment (s=0)
        #pragma unroll
        for (int m = 0; m < 4; ++m) {
            bf16x8 wh = ldfrag(wlds + m * 512 + l * 4);
            bf16x8 wl = ldfrag(wlds + m * 512 + 256 + l * 4);
            FragU bh, bl; bh.q = h0; bl.q = l0;
            acc1[m] = mfma16(wh, bh.v, acc1[m]);
            acc1[m] = mfma16(wl, bh.v, acc1[m]);
            acc1[m] = mfma16(wh, bl.v, acc1[m]);
        }
        // layer 1, x-dst segment (s=1)
        #pragma unroll
        for (int m = 0; m < 4; ++m) {
            bf16x8 wh = ldfrag(wlds + (4 + m) * 512 + l * 4);
            bf16x8 wl = ldfrag(wlds + (4 + m) * 512 + 256 + l * 4);
            FragU bh, bl; bh.q = h1; bl.q = l1;
            acc1[m] = mfma16(wh, bh.v, acc1[m]);
            acc1[m] = mfma16(wl, bh.v, acc1[m]);
            acc1[m] = mfma16(wh, bl.v, acc1[m]);
        }
        // layer 1, ea segment (s=2)
        FragU beh, bel;
        fsplit2(v0[0], v0[1], beh.u[0], bel.u[0]);
        fsplit2(v0[2], v0[3], beh.u[1], bel.u[1]);
        fsplit2(v1[0], v1[1], beh.u[2], bel.u[2]);
        fsplit2(v1[2], v1[3], beh.u[3], bel.u[3]);
        #pragma unroll
        for (int m = 0; m < 4; ++m) {
            bf16x8 wh = ldfrag(wlds + (8 + m) * 512 + l * 4);
            bf16x8 wl = ldfrag(wlds + (8 + m) * 512 + 256 + l * 4);
            acc1[m] = mfma16(wh, beh.v, acc1[m]);
            acc1[m] = mfma16(wl, beh.v, acc1[m]);
            acc1[m] = mfma16(wh, bel.v, acc1[m]);
        }

        // B2 frags: relu + split, lane-local (k-order matches permuted W2)
        FragU b2h[2], b2l[2];
        #pragma unroll
        for (int s2 = 0; s2 < 2; ++s2)
            #pragma unroll
            for (int p = 0; p < 4; ++p) {
                int m = 2 * s2 + (p >> 1);
                int r = (2 * p) & 3;
                float a = fmaxf(acc1[m][r], 0.0f);
                float c = fmaxf(acc1[m][r + 1], 0.0f);
                fsplit2(a, c, b2h[s2].u[p], b2l[s2].u[p]);
            }

        // layer 2 (bias from LDS)
        f32x4 acc2[2];
        acc2[0] = *(const f32x4*)(blds + 64 + lg * 4);
        acc2[1] = *(const f32x4*)(blds + 80 + lg * 4);
        #pragma unroll
        for (int s2 = 0; s2 < 2; ++s2)
            #pragma unroll
            for (int n2 = 0; n2 < 2; ++n2) {
                bf16x8 wh = ldfrag(wlds + 6144 + (s2 * 2 + n2) * 512 + l * 4);
                bf16x8 wl = ldfrag(wlds + 6144 + (s2 * 2 + n2) * 512 + 256 + l * 4);
                acc2[n2] = mfma16(wh, b2h[s2].v, acc2[n2]);
                acc2[n2] = mfma16(wl, b2h[s2].v, acc2[n2]);
                acc2[n2] = mfma16(wh, b2l[s2].v, acc2[n2]);
            }

        // store (lane owns edge lm of this half) + eagg accumulate
        int local = toff + lm;
        if (local < (int)(gend - e0)) {
            float* po = ea_out + (e0 + local) * FD + lg * 4;
            *(f32x4*)po        = acc2[0];
            *(f32x4*)(po + 16) = acc2[1];
            eacc0 += acc2[0];
            eacc1 += acc2[1];
        }
    };

    int nrr[2], ncc[2];
    #pragma unroll
    for (int t = 0; t < 2; ++t) {
        long e = gbase + (long)j0 * 128 + wid * 32 + t * 16 + lm;
        if (e >= gend) e = gend - 1;
        nrr[t] = rowi[e]; ncc[t] = coli[e];
    }

    for (int lt = j0; lt < EDGE_TPG; lt += 64) {
        int rr0 = nrr[0], rr1 = nrr[1], cc0 = ncc[0], cc1 = ncc[1];
        int nlt = lt + 64;
        if (nlt < EDGE_TPG) {
            #pragma unroll
            for (int t = 0; t < 2; ++t) {
                long e = gbase + (long)nlt * 128 + wid * 32 + t * 16 + lm;
                if (e >= gend) e = gend - 1;
                nrr[t] = rowi[e]; ncc[t] = coli[e];
            }
        }
        const long e0 = gbase + (long)lt * 128 + wid * 32;

        // issue ALL gathers for both halves up front
        const unsigned int* pr0 = x_sp + (long)rr0 * 32;
        const unsigned int* pc0 = x_sp + (long)cc0 * 32;
        const unsigned int* pr1 = x_sp + (long)rr1 * 32;
        const unsigned int* pc1 = x_sp + (long)cc1 * 32;
        u32x4 h00 = *(const u32x4*)(pr0 + lg * 4);
        u32x4 l00 = *(const u32x4*)(pr0 + 16 + lg * 4);
        u32x4 h01 = *(const u32x4*)(pc0 + lg * 4);
        u32x4 l01 = *(const u32x4*)(pc0 + 16 + lg * 4);
        u32x4 h10 = *(const u32x4*)(pr1 + lg * 4);
        u32x4 l10 = *(const u32x4*)(pr1 + 16 + lg * 4);
        u32x4 h11 = *(const u32x4*)(pc1 + lg * 4);
        u32x4 l11 = *(const u32x4*)(pc1 + 16 + lg * 4);

        long ee0 = e0 + lm;       if (ee0 >= gend) ee0 = gend - 1;
        long ee1 = e0 + 16 + lm;  if (ee1 >= gend) ee1 = gend - 1;
        const float* pe0 = ea_in + ee0 * FD + lg * 8;
        const float* pe1 = ea_in + ee1 * FD + lg * 8;
        f32x4 v00 = *(const f32x4*)pe0;
        f32x4 v01 = *(const f32x4*)(pe0 + 4);
        f32x4 v10 = *(const f32x4*)pe1;
        f32x4 v11 = *(const f32x4*)(pe1 + 4);

        do_half(e0, 0,  h00, l00, h01, l01, v00, v01);
        do_half(e0, 16, h10, l10, h11, l11, v10, v11);
    }

    // eagg: reduce across the 16 lm lanes, one atomic batch per wave
    #pragma unroll
    for (int r = 0; r < 4; ++r) {
        float v0 = eacc0[r], v1 = eacc1[r];
        v0 += __shfl_xor(v0, 1, 64); v1 += __shfl_xor(v1, 1, 64);
        v0 += __shfl_xor(v0, 2, 64); v1 += __shfl_xor(v1, 2, 64);
        v0 += __shfl_xor(v0, 4, 64); v1 += __shfl_xor(v1, 4, 64);
        v0 += __shfl_xor(v0, 8, 64); v1 += __shfl_xor(v1, 8, 64);
        if (lm == 0) {
            atomicAdd(&eagg[g * FD + lg * 4 + r], v0);
            atomicAdd(&eagg[g * FD + 16 + lg * 4 + r], v1);
        }
    }
}

// ---- aggregation: wave per node; 8 rows x 8 feat-quads (no NT — L2 reuse) ----
__global__ __launch_bounds__(256) void agg_kernel(
    const float* __restrict__ ea,
    const int* __restrict__ off,
    const int* __restrict__ csr,
    float* __restrict__ e_mean)
{
    int wid = threadIdx.x >> 6;
    int l   = threadIdx.x & 63;
    int rq  = l >> 3;
    int q   = l & 7;
    int n = blockIdx.x * 4 + wid;
    int s0 = off[n], s1 = off[n + 1];
    int deg = s1 - s0;

    f32x4 acc = {0.0f, 0.0f, 0.0f, 0.0f};
    if (deg > 0) {
        int cl = (l < deg) ? l : 0;
        int cidx = csr[s0 + cl];
        #pragma unroll
        for (int r = 0; r < 8; ++r) {
            int src = r * 8 + rq;
            int eid = __shfl(cidx, src, 64);
            if (src < deg) {
                f32x4 v = *(const f32x4*)(ea + (long)eid * FD + q * 4);
                acc += v;
            }
        }
        if (deg > 64) {
            for (int i = s0 + 64; i < s1; i += 8) {
                int ii = i + rq;
                if (ii < s1) {
                    int eid = csr[ii];
                    acc += *(const f32x4*)(ea + (long)eid * FD + q * 4);
                }
            }
        }
    }
    #pragma unroll
    for (int m = 8; m < 64; m <<= 1) {
        acc[0] += __shfl_xor(acc[0], m, 64);
        acc[1] += __shfl_xor(acc[1], m, 64);
        acc[2] += __shfl_xor(acc[2], m, 64);
        acc[3] += __shfl_xor(acc[3], m, 64);
    }
    float inv = 1.0f / (float)(deg > 1 ? deg : 1);
    if (l < 8) {
        f32x4 o = {acc[0] * inv, acc[1] * inv, acc[2] * inv, acc[3] * inv};
        *(f32x4*)(e_mean + (long)n * FD + q * 4) = o;
    }
}

// ---- MFMA node kernel (old structure, unchanged) ----
__global__ __launch_bounds__(256) void node_mfma_kernel(
    const float* __restrict__ x_in,
    const float* __restrict__ e_mean,
    const unsigned int* __restrict__ wsp,  // N1 @0 (rel), N2 @4096 (rel)
    const float* __restrict__ bn2,
    const float* __restrict__ cu_n,
    float* __restrict__ x_out,
    float* __restrict__ xagg)
{
    __shared__ unsigned int h_lds[4][32][68];

    const int tid = threadIdx.x;
    const int wid = tid >> 6;
    const int l   = tid & 63;
    const int lm  = l & 15;
    const int lg  = l >> 4;
    const int koff = lg * 8;

    bf16x8 w1h[2][4], w1l[2][4];
    #pragma unroll
    for (int s = 0; s < 2; ++s)
        #pragma unroll
        for (int n = 0; n < 4; ++n) {
            const unsigned int* p = wsp + (s * 4 + n) * 512 + l * 4;
            w1h[s][n] = ldfrag(p);
            w1l[s][n] = ldfrag(p + 256);
        }
    bf16x8 w2h[2][2], w2l[2][2];
    #pragma unroll
    for (int s = 0; s < 2; ++s)
        #pragma unroll
        for (int n = 0; n < 2; ++n) {
            const unsigned int* p = wsp + 4096 + (s * 2 + n) * 512 + l * 4;
            w2h[s][n] = ldfrag(p);
            w2l[s][n] = ldfrag(p + 256);
        }
    float bias2[2];
    bias2[0] = bn2[lm];
    bias2[1] = bn2[16 + lm];

    const int g  = blockIdx.x / NODE_TPG;
    const int lt = blockIdx.x - g * NODE_TPG;
    const int nb = lt * 128 + wid * 32;

    f32x4 va[2][2][2];
    #pragma unroll
    for (int t = 0; t < 2; ++t) {
        int rl = nb + t * 16 + lm;
        if (rl > NPG - 1) rl = NPG - 1;
        long node = (long)g * NPG + rl;
        const float* p0 = x_in   + node * FD + koff;
        const float* p1 = e_mean + node * FD + koff;
        va[t][0][0] = *(const f32x4*)p0; va[t][0][1] = *(const f32x4*)(p0 + 4);
        va[t][1][0] = *(const f32x4*)p1; va[t][1][1] = *(const f32x4*)(p1 + 4);
    }

    f32x4 acc1[2][4];
    #pragma unroll
    for (int n = 0; n < 4; ++n) {
        float b = cu_n[g * HD + n * 16 + lm];
        #pragma unroll
        for (int t = 0; t < 2; ++t) acc1[t][n] = (f32x4){b, b, b, b};
    }

    #pragma unroll
    for (int t = 0; t < 2; ++t) {
        #pragma unroll
        for (int s = 0; s < 2; ++s) {
            FragU ah, al;
            #pragma unroll
            for (int q = 0; q < 2; ++q)
                #pragma unroll
                for (int p = 0; p < 2; ++p)
                    fsplit2(va[t][s][q][2 * p], va[t][s][q][2 * p + 1],
                            ah.u[q * 2 + p], al.u[q * 2 + p]);
            #pragma unroll
            for (int n = 0; n < 4; ++n) {
                acc1[t][n] = mfma16(ah.v, w1h[s][n], acc1[t][n]);
                acc1[t][n] = mfma16(ah.v, w1l[s][n], acc1[t][n]);
                acc1[t][n] = mfma16(al.v, w1h[s][n], acc1[t][n]);
            }
        }
    }

    #pragma unroll
    for (int t = 0; t < 2; ++t)
        #pragma unroll
        for (int n = 0; n < 4; ++n)
            #pragma unroll
            for (int r = 0; r < 4; ++r)
                h_lds[wid][t * 16 + lg * 4 + r][n * 16 + lm] =
                    fpack_hl(fmaxf(acc1[t][n][r], 0.0f));
    asm volatile("s_waitcnt lgkmcnt(0)" ::: "memory");
    __builtin_amdgcn_sched_barrier(0);

    f32x4 acc2[2][2];
    #pragma unroll
    for (int n = 0; n < 2; ++n) {
        #pragma unroll
        for (int t = 0; t < 2; ++t) acc2[t][n] = (f32x4){bias2[n], bias2[n], bias2[n], bias2[n]};
    }
    #pragma unroll
    for (int t = 0; t < 2; ++t) {
        #pragma unroll
        for (int s = 0; s < 2; ++s) {
            const unsigned int* hp = &h_lds[wid][t * 16 + lm][s * 32 + koff];
            unsigned int u0 = hp[0], u1 = hp[1], u2 = hp[2], u3 = hp[3];
            unsigned int u4 = hp[4], u5 = hp[5], u6 = hp[6], u7 = hp[7];
            FragU ah, al;
            ah.u[0] = __builtin_amdgcn_perm(u1, u0, 0x05040100u);
            ah.u[1] = __builtin_amdgcn_perm(u3, u2, 0x05040100u);
            ah.u[2] = __builtin_amdgcn_perm(u5, u4, 0x05040100u);
            ah.u[3] = __builtin_amdgcn_perm(u7, u6, 0x05040100u);
            al.u[0] = __builtin_amdgcn_perm(u1, u0, 0x07060302u);
            al.u[1] = __builtin_amdgcn_perm(u3, u2, 0x07060302u);
            al.u[2] = __builtin_amdgcn_perm(u5, u4, 0x07060302u);
            al.u[3] = __builtin_amdgcn_perm(u7, u6, 0x07060302u);
            #pragma unroll
            for (int n = 0; n < 2; ++n) {
                acc2[t][n] = mfma16(ah.v, w2h[s][n], acc2[t][n]);
                acc2[t][n] = mfma16(ah.v, w2l[s][n], acc2[t][n]);
                acc2[t][n] = mfma16(al.v, w2h[s][n], acc2[t][n]);
            }
        }
    }

    #pragma unroll
    for (int t = 0; t < 2; ++t)
        #pragma unroll
        for (int r = 0; r < 4; ++r) {
            int rl = nb + t * 16 + lg * 4 + r;
            if (rl < NPG) {
                long node = (long)g * NPG + rl;
                x_out[node * FD + lm]      = acc2[t][0][r];
                x_out[node * FD + 16 + lm] = acc2[t][1][r];
            }
        }

    #pragma unroll
    for (int n = 0; n < 2; ++n) {
        float s = 0.0f;
        #pragma unroll
        for (int t = 0; t < 2; ++t)
            #pragma unroll
            for (int r = 0; r < 4; ++r) {
                int rl = nb + t * 16 + lg * 4 + r;
                s += (rl < NPG) ? acc2[t][n][r] : 0.0f;
            }
        s += __shfl_xor(s, 16, 64);
        s += __shfl_xor(s, 32, 64);
        if (lg == 0) atomicAdd(&xagg[g * FD + n * 16 + lm], s);
    }
}

// ---- global MLP + fused prep + agg zeroing ----
__global__ __launch_bounds__(1024) void global_kernel(
    const float* __restrict__ y_in,
    float* __restrict__ xagg, float* __restrict__ eagg,
    const float* __restrict__ Wg1, const float* __restrict__ bg1,
    const float* __restrict__ Wg2, const float* __restrict__ bg2,
    const float* __restrict__ We1, const float* __restrict__ be1,
    const float* __restrict__ Wn1, const float* __restrict__ bn1,
    float* __restrict__ y_out,
    float* __restrict__ cu_e, float* __restrict__ cu_n)
{
    __shared__ float in_lds[B_G][100];
    __shared__ float h_lds2[B_G][HD + 1];
    __shared__ float y_lds[B_G][FD];
    int tid = threadIdx.x;
    for (int idx = tid; idx < B_G * 96; idx += 1024) {
        int g2 = idx / 96, k = idx % 96;
        float v;
        if (k < 32)      v = xagg[g2 * 32 + k] * (1.0f / NPG);
        else if (k < 64) v = eagg[g2 * 32 + (k - 32)] * (1.0f / EPG);
        else             v = y_in[g2 * 32 + (k - 64)];
        in_lds[g2][k] = v;
    }
    __syncthreads();
    int g = tid >> 6, j = tid & 63;
    float h = bg1[j];
    for (int k = 0; k < 96; ++k)
        h = fmaf(in_lds[g][k], Wg1[k * HD + j], h);
    h_lds2[g][j] = fmaxf(h, 0.0f);
    __syncthreads();
    if (j < FD) {
        float o = bg2[j];
        for (int k = 0; k < HD; ++k)
            o = fmaf(h_lds2[g][k], Wg2[k * FD + j], o);
        y_out[g * FD + j] = o;
        y_lds[g][j] = o;
    }
    __syncthreads();
    float ae = be1[j];
    float an = bn1[j];
    for (int k = 0; k < FD; ++k) {
        float yv = y_lds[g][k];
        ae = fmaf(yv, We1[(96 + k) * HD + j], ae);
        an = fmaf(yv, Wn1[(64 + k) * HD + j], an);
    }
    cu_e[g * HD + j] = ae;
    cu_n[g * HD + j] = an;
    if (tid < B_G * FD)            xagg[tid] = 0.0f;
    else if (tid < 2 * B_G * FD)   eagg[tid - B_G * FD] = 0.0f;
}

// ---------------- launch ----------------

extern "C" void kernel_launch(void* const* d_in, const int* in_sizes, int n_in,
                              void* d_out, int out_size, void* d_ws, size_t ws_size,
                              hipStream_t stream)
{
    const float* x0  = (const float*)d_in[0];
    const float* ea0 = (const float*)d_in[1];
    const float* y0  = (const float*)d_in[2];
    const float* We1 = (const float*)d_in[3];
    const float* be1 = (const float*)d_in[4];
    const float* We2 = (const float*)d_in[5];
    const float* be2 = (const float*)d_in[6];
    const float* Wn1 = (const float*)d_in[7];
    const float* bn1 = (const float*)d_in[8];
    const float* Wn2 = (const float*)d_in[9];
    const float* bn2 = (const float*)d_in[10];
    const float* Wg1 = (const float*)d_in[11];
    const float* bg1 = (const float*)d_in[12];
    const float* Wg2 = (const float*)d_in[13];
    const float* bg2 = (const float*)d_in[14];
    const int*   ei  = (const int*)d_in[15];
    const int* rowi = ei;
    const int* coli = ei + NEDGES;

    float* out_x  = (float*)d_out;
    float* out_ea = out_x + (size_t)NNODES * FD;
    float* out_y  = out_ea + (size_t)NEDGES * FD;

    char* ws = (char*)d_ws;
    int*   off    = (int*)(ws + 0);            // 50001 ints
    int*   cursor = (int*)(ws + 200192);       // 50000 ints
    int*   csr    = (int*)(ws + 400384);       // 800000 ints
    float* xagg   = (float*)(ws + 3600384);    // 16*32
    float* eagg   = xagg + B_G * FD;           // 16*32
    float* cu_e   = (float*)(ws + 3604480);    // 16*64
    float* cu_n   = cu_e + B_G * HD;           // 16*64
    float* e_mean = (float*)(ws + 3612672);    // 6.4 MB
    unsigned int* wsp = (unsigned int*)(ws + 10012672); // 57344 B
    int*   bsum   = (int*)(ws + 10070016);     // 256 B
    unsigned int* x_sp = (unsigned int*)(ws + 10070272); // 6.4 MB

    wsplit_kernel<<<1, 1024, 0, stream>>>(We1, We2, Wn1, Wn2, wsp);
    hipMemsetAsync(cursor, 0, NNODES * sizeof(int), stream);
    count_kernel<<<(NEDGES + 255) / 256, 256, 0, stream>>>(coli, cursor);
    scan_blocks_kernel<<<49, 1024, 0, stream>>>(cursor, off, bsum, NNODES);
    scan_carry_kernel<<<1, 64, 0, stream>>>(bsum, off, 49, NNODES);
    scan_add_kernel<<<49, 1024, 0, stream>>>(bsum, off, NNODES);
    hipMemsetAsync(cursor, 0, NNODES * sizeof(int), stream);
    fill_kernel<<<(NEDGES + 255) / 256, 256, 0, stream>>>(coli, off, cursor, csr);

    prep_kernel<<<1, 1024, 0, stream>>>(y0, We1, be1, Wn1, bn1,
                                        cu_e, cu_n, xagg, eagg);

    for (int it = 0; it < NITER; ++it) {
        const float* xc  = (it == 0) ? x0  : out_x;
        const float* eac = (it == 0) ? ea0 : out_ea;
        const float* yc  = (it == 0) ? y0  : out_y;

        xsplit_kernel<<<(NNODES * 4 + 255) / 256, 256, 0, stream>>>(xc, x_sp);
        edge_mfma_kernel<<<EDGE_BLOCKS, 256, 0, stream>>>(x_sp, eac, rowi, coli,
                                                          wsp, be2, cu_e,
                                                          out_ea, eagg);
        agg_kernel<<<NNODES / 4, 256, 0, stream>>>(out_ea, off, csr, e_mean);
        node_mfma_kernel<<<NODE_BLOCKS, 256, 0, stream>>>(xc, e_mean,
                                                          wsp + 8192, bn2, cu_n,
                                                          out_x, xagg);
        global_kernel<<<1, 1024, 0, stream>>>(yc, xagg, eagg,
                                              Wg1, bg1, Wg2, bg2,
                                              We1, be1, Wn1, bn1,
                                              out_y, cu_e, cu_n);
    }
}